// Round 2
// baseline (7652.817 us; speedup 1.0000x reference)
//
#include <hip/hip_runtime.h>
#include <hip/hip_bf16.h>
#include <math.h>

#define NUSER 20000
#define NITEM 20000
#define NTOT  40000
#define DD    128
#define HH    4
#define TT    5
#define MMEM  8
#define EUI   40000
#define ET    16000

// order-preserving float->uint encoding for atomicMax on floats
__device__ __forceinline__ unsigned fenc(float f){
  unsigned u = __float_as_uint(f);
  return (u & 0x80000000u) ? ~u : (u | 0x80000000u);
}
__device__ __forceinline__ float fdec(unsigned u){
  u = (u & 0x80000000u) ? (u & 0x7fffffffu) : ~u;
  return __uint_as_float(u);
}

// ---------- generic tiled GEMM: C = act(A_eff @ B^T + bias) ----------
// A_eff[r,k]:
//   coefp != 0 : coefp[r*8 + (k>>7)] * A[row*128 + (k&127)]   (row = gather(r))
//   else       : A[row*lda + k]  (+ abias[k], then elu if aelu)
// B[k,o]:
//   bmode==0 : B[o*K + k]               (W stored (out,in) row-major)
//   bmode==1 : B[(k>>7)*16384 + o*128 + (k&127)]   (Ww stored (M,Do,Di))
// epilogue: sidx!=0 -> atomicAdd C[sidx[r]*ldc + c]; accum -> C += ; else C =
__global__ __launch_bounds__(256) void k_gemm(
    const float* __restrict__ A, int lda,
    const int* __restrict__ gidx, int goff,
    const float* __restrict__ coefp,
    const float* __restrict__ abias, int aelu,
    const float* __restrict__ B, int bmode,
    const float* __restrict__ bias,
    float* __restrict__ C, int ldc,
    const int* __restrict__ sidx,
    int accum, int act,
    int M, int K)
{
  __shared__ float As[16][68];
  __shared__ float Bs[16][68];
  int tid = threadIdx.x;
  int r0 = blockIdx.x * 64, c0 = blockIdx.y * 64;
  int skk = tid & 15, sq = tid >> 4;
  int tr = (tid >> 4) << 2;
  int tc = (tid & 15) << 2;
  float acc[4][4];
  #pragma unroll
  for (int i=0;i<4;i++)
    #pragma unroll
    for (int j=0;j<4;j++) acc[i][j]=0.f;

  for (int k0=0;k0<K;k0+=16){
    #pragma unroll
    for (int j=0;j<4;j++){
      int rr = sq + j*16;
      int r = r0 + rr, k = k0 + skk;
      float v = 0.f;
      if (r < M){
        int row = gidx ? (gidx[r] + goff) : r;
        if (coefp){
          v = coefp[(size_t)r*8 + (k>>7)] * A[(size_t)row*128 + (k&127)];
        } else {
          v = A[(size_t)row*lda + k];
          if (abias){ v += abias[k]; if (aelu) v = v>0.f ? v : expm1f(v); }
        }
      }
      As[skk][rr] = v;
    }
    #pragma unroll
    for (int j=0;j<4;j++){
      int oo = sq + j*16;
      int o = c0 + oo, k = k0 + skk;
      float v;
      if (bmode==0) v = B[(size_t)o*K + k];
      else          v = B[(size_t)(k>>7)*16384 + (size_t)o*128 + (k&127)];
      Bs[skk][oo] = v;
    }
    __syncthreads();
    #pragma unroll
    for (int kk=0;kk<16;kk++){
      float a[4], b[4];
      #pragma unroll
      for (int i=0;i<4;i++) a[i]=As[kk][tr+i];
      #pragma unroll
      for (int i=0;i<4;i++) b[i]=Bs[kk][tc+i];
      #pragma unroll
      for (int i=0;i<4;i++)
        #pragma unroll
        for (int j=0;j<4;j++) acc[i][j] = fmaf(a[i], b[j], acc[i][j]);
    }
    __syncthreads();
  }
  #pragma unroll
  for (int i=0;i<4;i++){
    int r = r0 + tr + i;
    if (r >= M) continue;
    #pragma unroll
    for (int j=0;j<4;j++){
      int c = c0 + tc + j;
      float v = acc[i][j];
      if (bias) v += bias[c];
      if (act==1) v = v>0.f ? v : expm1f(v);
      else if (act==2) v = v>0.f ? v : 0.2f*v;
      if (sidx) atomicAdd(&C[(size_t)sidx[r]*ldc + c], v);
      else if (accum) C[(size_t)r*ldc + c] += v;
      else C[(size_t)r*ldc + c] = v;
    }
  }
}

// ---------- attention dot products: el/er over all nodes ----------
__global__ void k_attn(const float* __restrict__ F, const float* __restrict__ al,
                       const float* __restrict__ ar, float* __restrict__ el, float* __restrict__ er){
  int n = blockIdx.x, lane = threadIdx.x;
  const float* row = F + (size_t)n*512;
  #pragma unroll
  for (int h=0;h<HH;h++){
    float x1 = row[h*128+lane], x2 = row[h*128+64+lane];
    float vl = x1*al[h*128+lane] + x2*al[h*128+64+lane];
    float vr = x1*ar[h*128+lane] + x2*ar[h*128+64+lane];
    #pragma unroll
    for (int off=32;off;off>>=1){ vl += __shfl_xor(vl,off); vr += __shfl_xor(vr,off); }
    if (lane==0){ el[n*4+h]=vl; er[n*4+h]=vr; }
  }
}

// ---------- edge softmax pass 1: e = lrelu(el+er), segment max ----------
__global__ void k_edge1(const int* __restrict__ sIdx, const int* __restrict__ dIdx,
                        int sOff, int dOff, const float* __restrict__ el, const float* __restrict__ er,
                        float* __restrict__ ebuf, unsigned* __restrict__ emax, int E){
  int e = blockIdx.x*256+threadIdx.x; if (e>=E) return;
  int s = sIdx[e]+sOff, d = dIdx[e]+dOff;
  #pragma unroll
  for (int h=0;h<4;h++){
    float v = el[s*4+h] + er[d*4+h];
    v = v>0.f ? v : 0.2f*v;
    ebuf[e*4+h] = v;
    atomicMax(&emax[d*4+h], fenc(v));
  }
}

// ---------- pass 2: exp(e - max), segment sum ----------
__global__ void k_edge2(const int* __restrict__ dIdx, int dOff, float* __restrict__ ebuf,
                        const unsigned* __restrict__ emax, float* __restrict__ denom, int E){
  int e = blockIdx.x*256+threadIdx.x; if (e>=E) return;
  int d = dIdx[e]+dOff;
  #pragma unroll
  for (int h=0;h<4;h++){
    float ex = expf(ebuf[e*4+h] - fdec(emax[d*4+h]));
    ebuf[e*4+h] = ex;
    atomicAdd(&denom[d*4+h], ex);
  }
}

// ---------- pass 3: rst[dst] += a * F[src]  (32 threads per edge) ----------
__global__ void k_edge3(const int* __restrict__ sIdx, const int* __restrict__ dIdx,
                        int sOff, int dOff, const float* __restrict__ ebuf,
                        const float* __restrict__ denom, const float* __restrict__ F,
                        float* __restrict__ rst, int E){
  int gid = blockIdx.x*256+threadIdx.x;
  int e = gid >> 5;       // 32 threads per edge: 4 heads x 8 groups of 16 floats
  if (e >= E) return;
  int rem = gid & 31; int h = rem >> 3; int d4 = (rem & 7) << 4; // d4: 0,16,...,112
  int s = sIdx[e]+sOff, d = dIdx[e]+dOff;
  float a = ebuf[e*4+h] / denom[d*4+h];
  const float4* fp = (const float4*)(F + (size_t)s*512 + h*128 + d4);
  float* rp = rst + (size_t)d*512 + h*128 + d4;
  #pragma unroll
  for (int q=0;q<4;q++){
    float4 f = fp[q];
    atomicAdd(rp+q*4+0, a*f.x); atomicAdd(rp+q*4+1, a*f.y);
    atomicAdd(rp+q*4+2, a*f.z); atomicAdd(rp+q*4+3, a*f.w);
  }
}

// ---------- coef / ncoef: lrelu(x @ Wc^T + bc), M=8 outputs ----------
__global__ void k_coef(const float* __restrict__ feat, const int* __restrict__ idx,
                       const float* __restrict__ Wc, const float* __restrict__ bc,
                       float* __restrict__ outc, int cnt){
  int t = blockIdx.y;
  __shared__ float wS[MMEM*DD];
  __shared__ float bS[MMEM];
  for (int i=threadIdx.x;i<MMEM*DD;i+=128) wS[i] = Wc[(size_t)t*MMEM*DD + i];
  if (threadIdx.x < MMEM) bS[threadIdx.x] = bc[t*MMEM + threadIdx.x];
  __syncthreads();
  int e = blockIdx.x*128 + threadIdx.x; if (e >= cnt) return;
  int node = idx ? idx[(size_t)t*cnt + e] : e;
  float acc[MMEM];
  #pragma unroll
  for (int m=0;m<MMEM;m++) acc[m]=bS[m];
  const float* fr = feat + (size_t)node*DD;
  for (int d2=0; d2<DD; d2++){
    float v = fr[d2];
    #pragma unroll
    for (int m=0;m<MMEM;m++) acc[m] = fmaf(v, wS[m*DD+d2], acc[m]);
  }
  float* op = outc + ((size_t)t*cnt + e)*MMEM;
  #pragma unroll
  for (int m=0;m<MMEM;m++){ float v=acc[m]; op[m] = v>0.f ? v : 0.2f*v; }
}

// ---------- degree count ----------
__global__ void k_count(const int* __restrict__ dsts, float* __restrict__ cnt, int n){
  int i = blockIdx.x*256+threadIdx.x;
  if (i<n) atomicAdd(&cnt[dsts[i]], 1.f);
}

// ---------- memory LN: out = LN(s/max(cnt,1))*w + b + h_bias ----------
__global__ void k_memln(const float* __restrict__ s, const float* __restrict__ cnt,
                        const float* __restrict__ lw, const float* __restrict__ lb,
                        const float* __restrict__ hb, float* __restrict__ outp){
  int n = blockIdx.x, lane = threadIdx.x;
  float c = fmaxf(cnt[n], 1.f);
  float x1 = s[(size_t)n*128+lane]/c, x2 = s[(size_t)n*128+64+lane]/c;
  float t = x1+x2;
  #pragma unroll
  for (int off=32;off;off>>=1) t += __shfl_xor(t,off);
  float mu = t * (1.f/128.f);
  float d1=x1-mu, d2=x2-mu;
  float v = d1*d1+d2*d2;
  #pragma unroll
  for (int off=32;off;off>>=1) v += __shfl_xor(v,off);
  float r = rsqrtf(v*(1.f/128.f) + 1e-5f);
  outp[(size_t)n*128+lane]    = d1*r*lw[lane]    + lb[lane]    + hb[lane];
  outp[(size_t)n*128+64+lane] = d2*r*lw[64+lane] + lb[64+lane] + hb[64+lane];
}

// ---------- finalize: feat_next = lrelu(mem) + trans ----------
__global__ void k_final_feat(const float* __restrict__ mo, const float* __restrict__ tr,
                             float* __restrict__ o, int n){
  int i = blockIdx.x*256+threadIdx.x; if (i>=n) return;
  float v = mo[i]; v = v>0.f ? v : 0.2f*v;
  o[i] = v + tr[i];
}

// ---------- final LN over 384-wide concat ----------
__global__ void k_final_ln(const float* __restrict__ emb, const float* __restrict__ f1,
                           const float* __restrict__ f2, const float* __restrict__ w,
                           const float* __restrict__ b, float* __restrict__ out){
  int n = blockIdx.x, t = threadIdx.x;
  __shared__ float red[4];
  float x0 = emb[(size_t)n*128+t];
  float x1 = f1[(size_t)n*128+t];
  float x2 = f2[(size_t)n*128+t];
  float s = x0+x1+x2;
  #pragma unroll
  for (int off=32;off;off>>=1) s += __shfl_xor(s,off);
  if ((t&63)==0) red[t>>6] = s;
  __syncthreads();
  float mu = (red[0]+red[1]) * (1.f/384.f);
  float d0=x0-mu, d1=x1-mu, d2=x2-mu;
  float v = d0*d0+d1*d1+d2*d2;
  #pragma unroll
  for (int off=32;off;off>>=1) v += __shfl_xor(v,off);
  if ((t&63)==0) red[2+(t>>6)] = v;
  __syncthreads();
  float var = (red[2]+red[3]) * (1.f/384.f);
  float r = rsqrtf(var + 1e-5f);
  size_t o = (size_t)n*384;
  out[o+t]     = d0*r*w[t]     + b[t];
  out[o+128+t] = d1*r*w[128+t] + b[128+t];
  out[o+256+t] = d2*r*w[256+t] + b[256+t];
}

extern "C" void kernel_launch(void* const* d_in, const int* in_sizes, int n_in,
                              void* d_out, int out_size, void* d_ws, size_t ws_size,
                              hipStream_t stream)
{
  const float* emb   = (const float*)d_in[0];
  const float* fcW   = (const float*)d_in[1];
  const float* attl  = (const float*)d_in[2];
  const float* attr  = (const float*)d_in[3];
  const float* gbias = (const float*)d_in[4];
  const float* projW = (const float*)d_in[5];
  const float* projB = (const float*)d_in[6];
  const float* relWc = (const float*)d_in[7];
  const float* relbc = (const float*)d_in[8];
  const float* relWw = (const float*)d_in[9];
  const float* nodWc = (const float*)d_in[10];
  const float* nodbc = (const float*)d_in[11];
  const float* nodWw = (const float*)d_in[12];
  const float* hbias = (const float*)d_in[13];
  const float* mlnw  = (const float*)d_in[14];
  const float* mlnb  = (const float*)d_in[15];
  const float* flnw  = (const float*)d_in[16];
  const float* flnb  = (const float*)d_in[17];
  const int*  srcU  = (const int*)d_in[18];
  const int*  dstI  = (const int*)d_in[19];
  const int*  eSrc  = (const int*)d_in[20];
  const int*  eDst  = (const int*)d_in[21];
  float* out = (float*)d_out;

  char* wp = (char*)d_ws;
  auto alloc = [&](size_t bytes)->void* {
    void* p = (void*)wp; wp += (bytes + 511) & ~(size_t)511; return p;
  };
  float*    feat1 = (float*)alloc((size_t)NTOT*DD*4);
  float*    feat2 = (float*)alloc((size_t)NTOT*DD*4);
  float*    Fbuf  = (float*)alloc((size_t)NTOT*512*4);
  float*    rst   = (float*)alloc((size_t)NTOT*512*4);
  float*    trans = (float*)alloc((size_t)NTOT*DD*4);
  float*    elF   = (float*)alloc((size_t)NTOT*4*4);
  float*    erF   = (float*)alloc((size_t)NTOT*4*4);
  float*    ebuf  = (float*)alloc((size_t)EUI*4*4);
  unsigned* emax  = (unsigned*)alloc((size_t)NTOT*4*4);
  float*    denom = (float*)alloc((size_t)NTOT*4*4);
  // memory-layer buffers live inside rst (GAT is done with it... no — use Fbuf tail is unsafe;
  // Fbuf/rst are free after both directions complete, memory layer runs after)
  float* sAgg   = rst;                        // NTOT*128
  float* memO   = rst + (size_t)NTOT*DD;      // NTOT*128
  float* coefB  = rst + (size_t)2*NTOT*DD;    // T*E*8
  float* ncoefB = coefB + (size_t)TT*ET*8;    // NTOT*8
  float* cntB   = ncoefB + (size_t)NTOT*8;    // NTOT

  const float* feats[3] = {emb, feat1, feat2};
  for (int l=0; l<2; l++){
    const float* fin  = feats[l];
    float* fout = (float*)feats[l+1];

    for (int d=0; d<2; d++){
      const float* W = fcW + (size_t)(l*2+d)*512*DD;
      // F = feat @ W^T  (all N rows)
      k_gemm<<<dim3(NTOT/64, 512/64),256,0,stream>>>(
          fin,128, nullptr,0, nullptr, nullptr,0, W,0, nullptr,
          Fbuf,512, nullptr, 0,0, NTOT,128);
      k_attn<<<dim3(NTOT),64,0,stream>>>(Fbuf,
          attl+(size_t)(l*2+d)*512, attr+(size_t)(l*2+d)*512, elF, erF);
      hipMemsetAsync(emax, 0, (size_t)NTOT*16, stream);
      hipMemsetAsync(denom, 0, (size_t)NTOT*16, stream);
      int dOff = (d==0) ? 0 : NUSER;
      int sOff = (d==0) ? NUSER : 0;
      const int* sIdx = (d==0) ? dstI : srcU;
      const int* dIdx = (d==0) ? srcU : dstI;
      hipMemsetAsync(rst + (size_t)dOff*512, 0, (size_t)20000*512*4, stream);
      k_edge1<<<dim3((EUI+255)/256),256,0,stream>>>(sIdx,dIdx,sOff,dOff,elF,erF,ebuf,emax,EUI);
      k_edge2<<<dim3((EUI+255)/256),256,0,stream>>>(dIdx,dOff,ebuf,emax,denom,EUI);
      k_edge3<<<dim3((EUI*32+255)/256),256,0,stream>>>(sIdx,dIdx,sOff,dOff,ebuf,denom,Fbuf,rst,EUI);
      // trans_half = elu( elu(rst+gbias) @ projW^T + projB )
      k_gemm<<<dim3((20000+63)/64, 2),256,0,stream>>>(
          rst + (size_t)dOff*512,512, nullptr,0, nullptr,
          gbias+(size_t)(l*2+d)*512,1,
          projW+(size_t)(l*2+d)*DD*512,0, projB+(size_t)(l*2+d)*DD,
          trans + (size_t)dOff*DD,DD, nullptr, 0,1, 20000,512);
    }

    // ---- memory layer (rst buffer reused as scratch; GAT done with it) ----
    hipMemsetAsync(sAgg, 0, (size_t)NTOT*DD*4, stream);
    hipMemsetAsync(cntB, 0, (size_t)NTOT*4, stream);
    k_count<<<dim3((TT*ET+255)/256),256,0,stream>>>(eDst, cntB, TT*ET);
    k_coef<<<dim3((ET+127)/128, TT),128,0,stream>>>(fin, eDst,
        relWc+(size_t)l*TT*MMEM*DD, relbc+(size_t)l*TT*MMEM, coefB, ET);
    for (int t=0; t<TT; t++){
      k_gemm<<<dim3(ET/64, 2),256,0,stream>>>(
          fin,128, eSrc+(size_t)t*ET,0, coefB+(size_t)t*ET*8,
          nullptr,0, relWw+(size_t)(l*TT+t)*MMEM*DD*DD,1, nullptr,
          sAgg,DD, eDst+(size_t)t*ET, 0,0, ET, MMEM*DD);
    }
    k_memln<<<dim3(NTOT),64,0,stream>>>(sAgg, cntB, mlnw+(size_t)l*DD, mlnb+(size_t)l*DD,
                                        hbias+(size_t)l*DD, memO);
    k_coef<<<dim3((NTOT+127)/128, 1),128,0,stream>>>(fin, nullptr,
        nodWc+(size_t)l*MMEM*DD, nodbc+(size_t)l*MMEM, ncoefB, NTOT);
    k_gemm<<<dim3(NTOT/64, 2),256,0,stream>>>(
        fin,128, nullptr,0, ncoefB, nullptr,0,
        nodWw+(size_t)l*MMEM*DD*DD,1, nullptr,
        memO,DD, nullptr, 1,0, NTOT, MMEM*DD);
    k_final_feat<<<dim3((NTOT*DD+255)/256),256,0,stream>>>(memO, trans, fout, NTOT*DD);
  }

  k_final_ln<<<dim3(NTOT),128,0,stream>>>(emb, feat1, feat2, flnw, flnb, out);
}

// Round 3
// 3158.850 us; speedup vs baseline: 2.4227x; 2.4227x over previous
//
#include <hip/hip_runtime.h>
#include <hip/hip_bf16.h>
#include <math.h>

#define NUSER 20000
#define NITEM 20000
#define NTOT  40000
#define DD    128
#define HH    4
#define TT    5
#define MMEM  8
#define EUI   40000
#define ET    16000

// ---------- generic tiled GEMM: C = act(A_eff @ B^T + bias) ----------
// A_eff[r,k]:
//   coefp != 0 : coefp[r*8 + (k>>7)] * A[row*128 + (k&127)]   (row = gather(r))
//   else       : A[row*lda + k]  (+ abias[k], then elu if aelu)
// B[k,o]:
//   bmode==0 : B[o*K + k]               (W stored (out,in) row-major)
//   bmode==1 : B[(k>>7)*16384 + o*128 + (k&127)]   (Ww stored (M,Do,Di))
// epilogue: sidx!=0 -> atomicAdd C[sidx[r]*ldc + c]; accum -> C += ; else C =
__global__ __launch_bounds__(256) void k_gemm(
    const float* __restrict__ A, int lda,
    const int* __restrict__ gidx, int goff,
    const float* __restrict__ coefp,
    const float* __restrict__ abias, int aelu,
    const float* __restrict__ B, int bmode,
    const float* __restrict__ bias,
    float* __restrict__ C, int ldc,
    const int* __restrict__ sidx,
    int accum, int act,
    int M, int K)
{
  __shared__ float As[16][68];
  __shared__ float Bs[16][68];
  int tid = threadIdx.x;
  int r0 = blockIdx.x * 64, c0 = blockIdx.y * 64;
  int skk = tid & 15, sq = tid >> 4;
  int tr = (tid >> 4) << 2;
  int tc = (tid & 15) << 2;
  float acc[4][4];
  #pragma unroll
  for (int i=0;i<4;i++)
    #pragma unroll
    for (int j=0;j<4;j++) acc[i][j]=0.f;

  for (int k0=0;k0<K;k0+=16){
    #pragma unroll
    for (int j=0;j<4;j++){
      int rr = sq + j*16;
      int r = r0 + rr, k = k0 + skk;
      float v = 0.f;
      if (r < M){
        int row = gidx ? (gidx[r] + goff) : r;
        if (coefp){
          v = coefp[(size_t)r*8 + (k>>7)] * A[(size_t)row*128 + (k&127)];
        } else {
          v = A[(size_t)row*lda + k];
          if (abias){ v += abias[k]; if (aelu) v = v>0.f ? v : expm1f(v); }
        }
      }
      As[skk][rr] = v;
    }
    #pragma unroll
    for (int j=0;j<4;j++){
      int oo = sq + j*16;
      int o = c0 + oo, k = k0 + skk;
      float v;
      if (bmode==0) v = B[(size_t)o*K + k];
      else          v = B[(size_t)(k>>7)*16384 + (size_t)o*128 + (k&127)];
      Bs[skk][oo] = v;
    }
    __syncthreads();
    #pragma unroll
    for (int kk=0;kk<16;kk++){
      float a[4], b[4];
      #pragma unroll
      for (int i=0;i<4;i++) a[i]=As[kk][tr+i];
      #pragma unroll
      for (int i=0;i<4;i++) b[i]=Bs[kk][tc+i];
      #pragma unroll
      for (int i=0;i<4;i++)
        #pragma unroll
        for (int j=0;j<4;j++) acc[i][j] = fmaf(a[i], b[j], acc[i][j]);
    }
    __syncthreads();
  }
  #pragma unroll
  for (int i=0;i<4;i++){
    int r = r0 + tr + i;
    if (r >= M) continue;
    #pragma unroll
    for (int j=0;j<4;j++){
      int c = c0 + tc + j;
      float v = acc[i][j];
      if (bias) v += bias[c];
      if (act==1) v = v>0.f ? v : expm1f(v);
      else if (act==2) v = v>0.f ? v : 0.2f*v;
      if (sidx) atomicAdd(&C[(size_t)sidx[r]*ldc + c], v);
      else if (accum) C[(size_t)r*ldc + c] += v;
      else C[(size_t)r*ldc + c] = v;
    }
  }
}

// ---------- attention dot products: el/er over all nodes ----------
__global__ void k_attn(const float* __restrict__ F, const float* __restrict__ al,
                       const float* __restrict__ ar, float* __restrict__ el, float* __restrict__ er){
  int n = blockIdx.x, lane = threadIdx.x;
  const float* row = F + (size_t)n*512;
  #pragma unroll
  for (int h=0;h<HH;h++){
    float x1 = row[h*128+lane], x2 = row[h*128+64+lane];
    float vl = x1*al[h*128+lane] + x2*al[h*128+64+lane];
    float vr = x1*ar[h*128+lane] + x2*ar[h*128+64+lane];
    #pragma unroll
    for (int off=32;off;off>>=1){ vl += __shfl_xor(vl,off); vr += __shfl_xor(vr,off); }
    if (lane==0){ el[n*4+h]=vl; er[n*4+h]=vr; }
  }
}

// ---------- CSR build: histogram ----------
__global__ void k_hist(const int* __restrict__ dIdx, int* __restrict__ cnt, int E){
  int e = blockIdx.x*256+threadIdx.x;
  if (e<E) atomicAdd(&cnt[dIdx[e]], 1);
}

// ---------- CSR build: single-block exclusive scan (n <= ~40k) ----------
__global__ __launch_bounds__(1024) void k_scan(const int* __restrict__ in,
                                               int* __restrict__ out, int n){
  __shared__ int wsum[16];
  __shared__ int carry;
  int tidx = threadIdx.x, lane = tidx & 63, w = tidx >> 6;
  if (tidx == 0) carry = 0;
  __syncthreads();
  for (int base = 0; base < n; base += 1024){
    int i = base + tidx;
    int v = (i < n) ? in[i] : 0;
    int x = v;
    #pragma unroll
    for (int off = 1; off < 64; off <<= 1){
      int t = __shfl_up(x, off);
      if (lane >= off) x += t;
    }
    if (lane == 63) wsum[w] = x;
    __syncthreads();
    if (w == 0 && lane < 16){
      int t = wsum[lane];
      #pragma unroll
      for (int off=1; off<16; off<<=1){
        int u = __shfl_up(t, off, 16);
        if (lane >= off) t += u;
      }
      wsum[lane] = t;
    }
    __syncthreads();
    int woff = (w == 0) ? 0 : wsum[w-1];
    int excl = carry + woff + x - v;
    if (i < n) out[i] = excl;
    __syncthreads();
    if (tidx == 1023) carry = carry + wsum[15];
    __syncthreads();
  }
  if (tidx == 0) out[n] = carry;
}

// ---------- CSR build: scatter edge src ids into buckets ----------
__global__ void k_csr_scatter(const int* __restrict__ sIdx, const int* __restrict__ dIdx,
                              int sOff, const int* __restrict__ rowptr,
                              int* __restrict__ cursor, int* __restrict__ col, int E){
  int e = blockIdx.x*256+threadIdx.x; if (e>=E) return;
  int d = dIdx[e];
  int pos = rowptr[d] + atomicAdd(&cursor[d], 1);
  col[pos] = sIdx[e] + sOff;
}

// ---------- fused GAT aggregation: online softmax + gather, 1 wave/dst ----------
__global__ __launch_bounds__(64) void k_gat_gather(
    const int* __restrict__ rowptr, const int* __restrict__ col,
    const float* __restrict__ el, const float* __restrict__ er,
    const float* __restrict__ F, float* __restrict__ rst,
    int dOff, int n_dst)
{
  int dl = blockIdx.x;
  int dn = dl + dOff;
  int lane = threadIdx.x;
  int h = lane >> 4;
  int off = (lane & 15) << 3;       // 8 floats per lane
  float erh = er[dn*4 + h];
  float m = -INFINITY, den = 0.f;
  float acc[8];
  #pragma unroll
  for (int i=0;i<8;i++) acc[i]=0.f;
  int jb = rowptr[dl], je = rowptr[dl+1];
  for (int j=jb; j<je; j++){
    int s = col[j];
    float e = el[s*4+h] + erh;
    e = e > 0.f ? e : 0.2f*e;
    float mn = fmaxf(m, e);
    float sc = __expf(m - mn);
    float wj = __expf(e - mn);
    den = den*sc + wj;
    m = mn;
    const float4* fp = (const float4*)(F + (size_t)s*512 + h*128 + off);
    float4 f0 = fp[0], f1 = fp[1];
    acc[0]=acc[0]*sc + wj*f0.x; acc[1]=acc[1]*sc + wj*f0.y;
    acc[2]=acc[2]*sc + wj*f0.z; acc[3]=acc[3]*sc + wj*f0.w;
    acc[4]=acc[4]*sc + wj*f1.x; acc[5]=acc[5]*sc + wj*f1.y;
    acc[6]=acc[6]*sc + wj*f1.z; acc[7]=acc[7]*sc + wj*f1.w;
  }
  float inv = den > 0.f ? 1.f/den : 0.f;
  float* rp = rst + (size_t)dn*512 + h*128 + off;
  float4 o0 = make_float4(acc[0]*inv, acc[1]*inv, acc[2]*inv, acc[3]*inv);
  float4 o1 = make_float4(acc[4]*inv, acc[5]*inv, acc[6]*inv, acc[7]*inv);
  ((float4*)rp)[0] = o0;
  ((float4*)rp)[1] = o1;
}

// ---------- coef / ncoef: lrelu(x @ Wc^T + bc), M=8 outputs ----------
__global__ void k_coef(const float* __restrict__ feat, const int* __restrict__ idx,
                       const float* __restrict__ Wc, const float* __restrict__ bc,
                       float* __restrict__ outc, int cnt){
  int t = blockIdx.y;
  __shared__ float wS[MMEM*DD];
  __shared__ float bS[MMEM];
  for (int i=threadIdx.x;i<MMEM*DD;i+=128) wS[i] = Wc[(size_t)t*MMEM*DD + i];
  if (threadIdx.x < MMEM) bS[threadIdx.x] = bc[t*MMEM + threadIdx.x];
  __syncthreads();
  int e = blockIdx.x*128 + threadIdx.x; if (e >= cnt) return;
  int node = idx ? idx[(size_t)t*cnt + e] : e;
  float acc[MMEM];
  #pragma unroll
  for (int m=0;m<MMEM;m++) acc[m]=bS[m];
  const float* fr = feat + (size_t)node*DD;
  for (int d2=0; d2<DD; d2++){
    float v = fr[d2];
    #pragma unroll
    for (int m=0;m<MMEM;m++) acc[m] = fmaf(v, wS[m*DD+d2], acc[m]);
  }
  float* op = outc + ((size_t)t*cnt + e)*MMEM;
  #pragma unroll
  for (int m=0;m<MMEM;m++){ float v=acc[m]; op[m] = v>0.f ? v : 0.2f*v; }
}

// ---------- degree count (float) ----------
__global__ void k_count(const int* __restrict__ dsts, float* __restrict__ cnt, int n){
  int i = blockIdx.x*256+threadIdx.x;
  if (i<n) atomicAdd(&cnt[dsts[i]], 1.f);
}

// ---------- memory LN: out = LN(s/max(cnt,1))*w + b + h_bias ----------
__global__ void k_memln(const float* __restrict__ s, const float* __restrict__ cnt,
                        const float* __restrict__ lw, const float* __restrict__ lb,
                        const float* __restrict__ hb, float* __restrict__ outp){
  int n = blockIdx.x, lane = threadIdx.x;
  float c = fmaxf(cnt[n], 1.f);
  float x1 = s[(size_t)n*128+lane]/c, x2 = s[(size_t)n*128+64+lane]/c;
  float t = x1+x2;
  #pragma unroll
  for (int off=32;off;off>>=1) t += __shfl_xor(t,off);
  float mu = t * (1.f/128.f);
  float d1=x1-mu, d2=x2-mu;
  float v = d1*d1+d2*d2;
  #pragma unroll
  for (int off=32;off;off>>=1) v += __shfl_xor(v,off);
  float r = rsqrtf(v*(1.f/128.f) + 1e-5f);
  outp[(size_t)n*128+lane]    = d1*r*lw[lane]    + lb[lane]    + hb[lane];
  outp[(size_t)n*128+64+lane] = d2*r*lw[64+lane] + lb[64+lane] + hb[64+lane];
}

// ---------- finalize: feat_next = lrelu(mem) + trans ----------
__global__ void k_final_feat(const float* __restrict__ mo, const float* __restrict__ tr,
                             float* __restrict__ o, int n){
  int i = blockIdx.x*256+threadIdx.x; if (i>=n) return;
  float v = mo[i]; v = v>0.f ? v : 0.2f*v;
  o[i] = v + tr[i];
}

// ---------- final LN over 384-wide concat ----------
__global__ void k_final_ln(const float* __restrict__ emb, const float* __restrict__ f1,
                           const float* __restrict__ f2, const float* __restrict__ w,
                           const float* __restrict__ b, float* __restrict__ out){
  int n = blockIdx.x, t = threadIdx.x;
  __shared__ float red[4];
  float x0 = emb[(size_t)n*128+t];
  float x1 = f1[(size_t)n*128+t];
  float x2 = f2[(size_t)n*128+t];
  float s = x0+x1+x2;
  #pragma unroll
  for (int off=32;off;off>>=1) s += __shfl_xor(s,off);
  if ((t&63)==0) red[t>>6] = s;
  __syncthreads();
  float mu = (red[0]+red[1]) * (1.f/384.f);
  float d0=x0-mu, d1=x1-mu, d2=x2-mu;
  float v = d0*d0+d1*d1+d2*d2;
  #pragma unroll
  for (int off=32;off;off>>=1) v += __shfl_xor(v,off);
  if ((t&63)==0) red[2+(t>>6)] = v;
  __syncthreads();
  float var = (red[2]+red[3]) * (1.f/384.f);
  float r = rsqrtf(var + 1e-5f);
  size_t o = (size_t)n*384;
  out[o+t]     = d0*r*w[t]     + b[t];
  out[o+128+t] = d1*r*w[128+t] + b[128+t];
  out[o+256+t] = d2*r*w[256+t] + b[256+t];
}

extern "C" void kernel_launch(void* const* d_in, const int* in_sizes, int n_in,
                              void* d_out, int out_size, void* d_ws, size_t ws_size,
                              hipStream_t stream)
{
  const float* emb   = (const float*)d_in[0];
  const float* fcW   = (const float*)d_in[1];
  const float* attl  = (const float*)d_in[2];
  const float* attr  = (const float*)d_in[3];
  const float* gbias = (const float*)d_in[4];
  const float* projW = (const float*)d_in[5];
  const float* projB = (const float*)d_in[6];
  const float* relWc = (const float*)d_in[7];
  const float* relbc = (const float*)d_in[8];
  const float* relWw = (const float*)d_in[9];
  const float* nodWc = (const float*)d_in[10];
  const float* nodbc = (const float*)d_in[11];
  const float* nodWw = (const float*)d_in[12];
  const float* hbias = (const float*)d_in[13];
  const float* mlnw  = (const float*)d_in[14];
  const float* mlnb  = (const float*)d_in[15];
  const float* flnw  = (const float*)d_in[16];
  const float* flnb  = (const float*)d_in[17];
  const int*  srcU  = (const int*)d_in[18];
  const int*  dstI  = (const int*)d_in[19];
  const int*  eSrc  = (const int*)d_in[20];
  const int*  eDst  = (const int*)d_in[21];
  float* out = (float*)d_out;

  char* wp = (char*)d_ws;
  auto alloc = [&](size_t bytes)->void* {
    void* p = (void*)wp; wp += (bytes + 511) & ~(size_t)511; return p;
  };
  float* feat1 = (float*)alloc((size_t)NTOT*DD*4);
  float* feat2 = (float*)alloc((size_t)NTOT*DD*4);
  float* Fbuf  = (float*)alloc((size_t)NTOT*512*4);
  float* rst   = (float*)alloc((size_t)NTOT*512*4);
  float* trans = (float*)alloc((size_t)NTOT*DD*4);
  float* elF   = (float*)alloc((size_t)NTOT*4*4);
  float* erF   = (float*)alloc((size_t)NTOT*4*4);
  // CSR for the two GAT directions (layer-independent)
  int* rpA  = (int*)alloc((size_t)(NUSER+1)*4);   // dst = users
  int* colA = (int*)alloc((size_t)EUI*4);
  int* rpB  = (int*)alloc((size_t)(NITEM+1)*4);   // dst = items
  int* colB = (int*)alloc((size_t)EUI*4);
  int* icnt = (int*)alloc((size_t)20000*4);
  int* icur = (int*)alloc((size_t)20000*4);
  // memory-layer buffers reuse rst region (free between GAT phases)
  float* sAgg   = rst;                        // NTOT*128
  float* memO   = rst + (size_t)NTOT*DD;      // NTOT*128
  float* coefB  = rst + (size_t)2*NTOT*DD;    // T*E*8
  float* ncoefB = coefB + (size_t)TT*ET*8;    // NTOT*8
  float* cntB   = ncoefB + (size_t)NTOT*8;    // NTOT

  // ---- build CSR for both GAT directions (edges fixed across layers) ----
  // direction 0: dst = users (srcU), src = items (dstI + NUSER)
  hipMemsetAsync(icnt, 0, 20000*4, stream);
  hipMemsetAsync(icur, 0, 20000*4, stream);
  k_hist<<<dim3((EUI+255)/256),256,0,stream>>>(srcU, icnt, EUI);
  k_scan<<<dim3(1),1024,0,stream>>>(icnt, rpA, NUSER);
  k_csr_scatter<<<dim3((EUI+255)/256),256,0,stream>>>(dstI, srcU, NUSER, rpA, icur, colA, EUI);
  // direction 1: dst = items (dstI), src = users (srcU + 0)
  hipMemsetAsync(icnt, 0, 20000*4, stream);
  hipMemsetAsync(icur, 0, 20000*4, stream);
  k_hist<<<dim3((EUI+255)/256),256,0,stream>>>(dstI, icnt, EUI);
  k_scan<<<dim3(1),1024,0,stream>>>(icnt, rpB, NITEM);
  k_csr_scatter<<<dim3((EUI+255)/256),256,0,stream>>>(srcU, dstI, 0, rpB, icur, colB, EUI);

  const float* feats[3] = {emb, feat1, feat2};
  for (int l=0; l<2; l++){
    const float* fin  = feats[l];
    float* fout = (float*)feats[l+1];

    for (int d=0; d<2; d++){
      const float* W = fcW + (size_t)(l*2+d)*512*DD;
      // F = feat @ W^T  (all N rows)
      k_gemm<<<dim3(NTOT/64, 512/64),256,0,stream>>>(
          fin,128, nullptr,0, nullptr, nullptr,0, W,0, nullptr,
          Fbuf,512, nullptr, 0,0, NTOT,128);
      k_attn<<<dim3(NTOT),64,0,stream>>>(Fbuf,
          attl+(size_t)(l*2+d)*512, attr+(size_t)(l*2+d)*512, elF, erF);
      int dOff = (d==0) ? 0 : NUSER;
      const int* rp  = (d==0) ? rpA : rpB;
      const int* col = (d==0) ? colA : colB;
      k_gat_gather<<<dim3(20000),64,0,stream>>>(rp, col, elF, erF, Fbuf, rst, dOff, 20000);
      // trans_half = elu( elu(rst+gbias) @ projW^T + projB )
      k_gemm<<<dim3((20000+63)/64, 2),256,0,stream>>>(
          rst + (size_t)dOff*512,512, nullptr,0, nullptr,
          gbias+(size_t)(l*2+d)*512,1,
          projW+(size_t)(l*2+d)*DD*512,0, projB+(size_t)(l*2+d)*DD,
          trans + (size_t)dOff*DD,DD, nullptr, 0,1, 20000,512);
    }

    // ---- memory layer (rst region reused as scratch; GAT done with it) ----
    hipMemsetAsync(sAgg, 0, (size_t)NTOT*DD*4, stream);
    hipMemsetAsync(cntB, 0, (size_t)NTOT*4, stream);
    k_count<<<dim3((TT*ET+255)/256),256,0,stream>>>(eDst, cntB, TT*ET);
    k_coef<<<dim3((ET+127)/128, TT),128,0,stream>>>(fin, eDst,
        relWc+(size_t)l*TT*MMEM*DD, relbc+(size_t)l*TT*MMEM, coefB, ET);
    for (int t=0; t<TT; t++){
      k_gemm<<<dim3(ET/64, 2),256,0,stream>>>(
          fin,128, eSrc+(size_t)t*ET,0, coefB+(size_t)t*ET*8,
          nullptr,0, relWw+(size_t)(l*TT+t)*MMEM*DD*DD,1, nullptr,
          sAgg,DD, eDst+(size_t)t*ET, 0,0, ET, MMEM*DD);
    }
    k_memln<<<dim3(NTOT),64,0,stream>>>(sAgg, cntB, mlnw+(size_t)l*DD, mlnb+(size_t)l*DD,
                                        hbias+(size_t)l*DD, memO);
    k_coef<<<dim3((NTOT+127)/128, 1),128,0,stream>>>(fin, nullptr,
        nodWc+(size_t)l*MMEM*DD, nodbc+(size_t)l*MMEM, ncoefB, NTOT);
    k_gemm<<<dim3(NTOT/64, 2),256,0,stream>>>(
        fin,128, nullptr,0, ncoefB, nullptr,0,
        nodWw+(size_t)l*MMEM*DD*DD,1, nullptr,
        memO,DD, nullptr, 1,0, NTOT, MMEM*DD);
    k_final_feat<<<dim3((NTOT*DD+255)/256),256,0,stream>>>(memO, trans, fout, NTOT*DD);
  }

  k_final_ln<<<dim3(NTOT),128,0,stream>>>(emb, feat1, feat2, flnw, flnb, out);
}

// Round 4
// 1558.619 us; speedup vs baseline: 4.9100x; 2.0267x over previous
//
#include <hip/hip_runtime.h>
#include <hip/hip_bf16.h>
#include <math.h>

typedef __hip_bfloat16 bf16;

#define NUSER 20000
#define NITEM 20000
#define NTOT  40000
#define DD    128
#define HH    4
#define TT    5
#define MMEM  8
#define EUI   40000
#define ET    16000

#define MP_N  40064   // NTOT padded to 128
#define MP_H  20096   // 20000 padded to 128

typedef __attribute__((ext_vector_type(8))) short short8;
typedef __attribute__((ext_vector_type(4))) float f32x4;

__device__ __forceinline__ void gload16(const bf16* g, bf16* l){
  __builtin_amdgcn_global_load_lds(
      (const __attribute__((address_space(1))) unsigned int*)g,
      (__attribute__((address_space(3))) unsigned int*)l, 16, 0, 0);
}

// ================= MFMA bf16 GEMM: C = act(A @ B^T + bias) =================
// A: [Mp x K] bf16 row-major (Mp multiple of 128, rows >= M zero-padded)
// B: [N x K]  bf16 row-major (N multiple of 128), K multiple of 32
// C: fp32 [M x ldc]; act==1 -> elu; accum -> C += v
__global__ __launch_bounds__(256) void k_mfma_gemm(
    const bf16* __restrict__ A, const bf16* __restrict__ B,
    const float* __restrict__ bias, float* __restrict__ C, int ldc,
    int M, int K, int act, int accum)
{
  __shared__ bf16 As[128*32];
  __shared__ bf16 Bs[128*32];
  int tid = threadIdx.x;
  int wave = tid >> 6, lane = tid & 63;
  int r0 = blockIdx.x * 128, c0 = blockIdx.y * 128;
  int wm = (wave >> 1) * 64, wn = (wave & 1) * 64;
  f32x4 acc[4][4];
  #pragma unroll
  for (int i=0;i<4;i++)
    #pragma unroll
    for (int j=0;j<4;j++) acc[i][j] = (f32x4){0.f,0.f,0.f,0.f};

  // staging: wave handles rows [wave*32, wave*32+32) of both A and B tiles.
  // instr q covers 16 rows: lane l -> row q*16 + (l>>2), col (l&3)*8 ; LDS dest = base + l*8 elems
  const bf16* Ag = A + (size_t)(r0 + wave*32 + (lane>>2))*K + (lane&3)*8;
  const bf16* Bg = B + (size_t)(c0 + wave*32 + (lane>>2))*K + (lane&3)*8;
  bf16* AsW = As + wave*32*32;
  bf16* BsW = Bs + wave*32*32;
  int lm = lane & 15, lq = lane >> 4;
  const bf16* Ard = As + (wm + lm)*32 + lq*8;
  const bf16* Brd = Bs + (wn + lm)*32 + lq*8;

  for (int k0 = 0; k0 < K; k0 += 32){
    gload16(Ag + k0,            AsW);
    gload16(Ag + 16*K + k0,     AsW + 16*32);
    gload16(Bg + k0,            BsW);
    gload16(Bg + 16*K + k0,     BsW + 16*32);
    __syncthreads();
    short8 af[4], bfv[4];
    #pragma unroll
    for (int i=0;i<4;i++) af[i]  = *(const short8*)(Ard + i*16*32);
    #pragma unroll
    for (int j=0;j<4;j++) bfv[j] = *(const short8*)(Brd + j*16*32);
    #pragma unroll
    for (int i=0;i<4;i++)
      #pragma unroll
      for (int j=0;j<4;j++)
        acc[i][j] = __builtin_amdgcn_mfma_f32_16x16x32_bf16(af[i], bfv[j], acc[i][j], 0, 0, 0);
    __syncthreads();
  }
  // C/D layout: col = lane&15, row = (lane>>4)*4 + reg
  #pragma unroll
  for (int i=0;i<4;i++){
    #pragma unroll
    for (int j=0;j<4;j++){
      int c = c0 + wn + j*16 + lm;
      #pragma unroll
      for (int rg=0; rg<4; rg++){
        int r = r0 + wm + i*16 + lq*4 + rg;
        if (r < M){
          float v = acc[i][j][rg];
          if (bias) v += bias[c];
          if (act==1) v = v>0.f ? v : expm1f(v);
          float* cp = &C[(size_t)r*ldc + c];
          if (accum) *cp += v; else *cp = v;
        }
      }
    }
  }
}

// ---------- fp32 -> bf16 with zero pad ----------
__global__ void k_f2b(const float* __restrict__ in, bf16* __restrict__ o, int nv, int nt){
  int i = blockIdx.x*256 + threadIdx.x;
  if (i < nt) o[i] = __float2bfloat16(i < nv ? in[i] : 0.f);
}

// ---------- repack Ww (M,Do,Di) -> B^T [Do x (M*Di)] bf16, per slice ----------
__global__ void k_repack(const float* __restrict__ in, bf16* __restrict__ o){
  int s = blockIdx.y;
  int g = blockIdx.x*256 + threadIdx.x;          // g = m*16384 + od*128 + i
  int m = g >> 14, od = (g >> 7) & 127, i = g & 127;
  o[(size_t)s*131072 + (size_t)od*1024 + m*128 + i] = __float2bfloat16(in[(size_t)s*131072 + g]);
}

// ---------- rstb = bf16(elu(rst_half + gbias)), rows padded to MP_H ----------
__global__ void k_rstb(const float* __restrict__ rst, const float* __restrict__ gb,
                       bf16* __restrict__ o){
  int r = blockIdx.x, t = threadIdx.x;          // 128 threads, 4 elems each
  int k = t*4;
  bf16* op = o + (size_t)r*512 + k;
  if (r < 20000){
    const float* ip = rst + (size_t)r*512 + k;
    #pragma unroll
    for (int q=0;q<4;q++){
      float v = ip[q] + gb[k+q];
      v = v>0.f ? v : expm1f(v);
      op[q] = __float2bfloat16(v);
    }
  } else {
    #pragma unroll
    for (int q=0;q<4;q++) op[q] = __float2bfloat16(0.f);
  }
}

// ---------- Aeff[e, m*128+i] = bf16(coef[e,m] * feat[src[e], i]) ----------
__global__ void k_aeff_rel(const float* __restrict__ feat, const int* __restrict__ src,
                           const float* __restrict__ coef, bf16* __restrict__ o, int E){
  int e = blockIdx.x*4 + (threadIdx.x >> 6);
  if (e >= E) return;
  int lane = threadIdx.x & 63;
  int m = lane >> 3, ib = (lane & 7) << 4;
  float cf = coef[(size_t)e*8 + m];
  const float* fr = feat + (size_t)src[e]*128 + ib;
  bf16* op = o + (size_t)e*1024 + m*128 + ib;
  #pragma unroll
  for (int q=0;q<16;q++) op[q] = __float2bfloat16(cf * fr[q]);
}

// ---------- Aeff2 for node-mem (chunk of 20000 rows, padded to MP_H) ----------
__global__ void k_aeff_node(const float* __restrict__ feat, const float* __restrict__ ncoef,
                            bf16* __restrict__ o, int base){
  int rl = blockIdx.x*4 + (threadIdx.x >> 6);
  if (rl >= MP_H) return;
  int lane = threadIdx.x & 63;
  int m = lane >> 3, ib = (lane & 7) << 4;
  bf16* op = o + (size_t)rl*1024 + m*128 + ib;
  if (rl < 20000){
    int n = base + rl;
    float cf = ncoef[(size_t)n*8 + m];
    const float* fr = feat + (size_t)n*128 + ib;
    #pragma unroll
    for (int q=0;q<16;q++) op[q] = __float2bfloat16(cf * fr[q]);
  } else {
    #pragma unroll
    for (int q=0;q<16;q++) op[q] = __float2bfloat16(0.f);
  }
}

// ---------- attention dot products ----------
__global__ void k_attn(const float* __restrict__ F, const float* __restrict__ al,
                       const float* __restrict__ ar, float* __restrict__ el, float* __restrict__ er){
  int n = blockIdx.x, lane = threadIdx.x;
  const float* row = F + (size_t)n*512;
  #pragma unroll
  for (int h=0;h<HH;h++){
    float x1 = row[h*128+lane], x2 = row[h*128+64+lane];
    float vl = x1*al[h*128+lane] + x2*al[h*128+64+lane];
    float vr = x1*ar[h*128+lane] + x2*ar[h*128+64+lane];
    #pragma unroll
    for (int off=32;off;off>>=1){ vl += __shfl_xor(vl,off); vr += __shfl_xor(vr,off); }
    if (lane==0){ el[n*4+h]=vl; er[n*4+h]=vr; }
  }
}

// ---------- CSR build ----------
__global__ void k_hist(const int* __restrict__ dIdx, int* __restrict__ cnt, int E){
  int e = blockIdx.x*256+threadIdx.x;
  if (e<E) atomicAdd(&cnt[dIdx[e]], 1);
}

__global__ __launch_bounds__(1024) void k_scan(const int* __restrict__ in,
                                               int* __restrict__ out, int n){
  __shared__ int wsum[16];
  __shared__ int carry;
  int tidx = threadIdx.x, lane = tidx & 63, w = tidx >> 6;
  if (tidx == 0) carry = 0;
  __syncthreads();
  for (int base = 0; base < n; base += 1024){
    int i = base + tidx;
    int v = (i < n) ? in[i] : 0;
    int x = v;
    #pragma unroll
    for (int off = 1; off < 64; off <<= 1){
      int t = __shfl_up(x, off);
      if (lane >= off) x += t;
    }
    if (lane == 63) wsum[w] = x;
    __syncthreads();
    if (w == 0 && lane < 16){
      int t = wsum[lane];
      #pragma unroll
      for (int off=1; off<16; off<<=1){
        int u = __shfl_up(t, off, 16);
        if (lane >= off) t += u;
      }
      wsum[lane] = t;
    }
    __syncthreads();
    int woff = (w == 0) ? 0 : wsum[w-1];
    int excl = carry + woff + x - v;
    if (i < n) out[i] = excl;
    __syncthreads();
    if (tidx == 1023) carry = carry + wsum[15];
    __syncthreads();
  }
  if (tidx == 0) out[n] = carry;
}

__global__ void k_csr_scatter(const int* __restrict__ sIdx, const int* __restrict__ dIdx,
                              int sOff, const int* __restrict__ rowptr,
                              int* __restrict__ cursor, int* __restrict__ col, int E){
  int e = blockIdx.x*256+threadIdx.x; if (e>=E) return;
  int d = dIdx[e];
  int pos = rowptr[d] + atomicAdd(&cursor[d], 1);
  col[pos] = sIdx[e] + sOff;
}

// scatter storing the edge id itself
__global__ void k_csr_scatter_eid(const int* __restrict__ dIdx, const int* __restrict__ rowptr,
                                  int* __restrict__ cursor, int* __restrict__ col, int E){
  int e = blockIdx.x*256+threadIdx.x; if (e>=E) return;
  int d = dIdx[e];
  int pos = rowptr[d] + atomicAdd(&cursor[d], 1);
  col[pos] = e;
}

// ---------- fused GAT aggregation: online softmax + gather, 1 wave/dst ----------
__global__ __launch_bounds__(64) void k_gat_gather(
    const int* __restrict__ rowptr, const int* __restrict__ col,
    const float* __restrict__ el, const float* __restrict__ er,
    const float* __restrict__ F, float* __restrict__ rst,
    int dOff, int n_dst)
{
  int dl = blockIdx.x;
  int dn = dl + dOff;
  int lane = threadIdx.x;
  int h = lane >> 4;
  int off = (lane & 15) << 3;
  float erh = er[dn*4 + h];
  float m = -INFINITY, den = 0.f;
  float acc[8];
  #pragma unroll
  for (int i=0;i<8;i++) acc[i]=0.f;
  int jb = rowptr[dl], je = rowptr[dl+1];
  for (int j=jb; j<je; j++){
    int s = col[j];
    float e = el[s*4+h] + erh;
    e = e > 0.f ? e : 0.2f*e;
    float mn = fmaxf(m, e);
    float sc = __expf(m - mn);
    float wj = __expf(e - mn);
    den = den*sc + wj;
    m = mn;
    const float4* fp = (const float4*)(F + (size_t)s*512 + h*128 + off);
    float4 f0 = fp[0], f1 = fp[1];
    acc[0]=acc[0]*sc + wj*f0.x; acc[1]=acc[1]*sc + wj*f0.y;
    acc[2]=acc[2]*sc + wj*f0.z; acc[3]=acc[3]*sc + wj*f0.w;
    acc[4]=acc[4]*sc + wj*f1.x; acc[5]=acc[5]*sc + wj*f1.y;
    acc[6]=acc[6]*sc + wj*f1.z; acc[7]=acc[7]*sc + wj*f1.w;
  }
  float inv = den > 0.f ? 1.f/den : 0.f;
  float* rp = rst + (size_t)dn*512 + h*128 + off;
  ((float4*)rp)[0] = make_float4(acc[0]*inv, acc[1]*inv, acc[2]*inv, acc[3]*inv);
  ((float4*)rp)[1] = make_float4(acc[4]*inv, acc[5]*inv, acc[6]*inv, acc[7]*inv);
}

// ---------- coef / ncoef: lrelu(x @ Wc^T + bc), M=8 outputs ----------
__global__ void k_coef(const float* __restrict__ feat, const int* __restrict__ idx,
                       const float* __restrict__ Wc, const float* __restrict__ bc,
                       float* __restrict__ outc, int cnt){
  int t = blockIdx.y;
  __shared__ float wS[MMEM*DD];
  __shared__ float bS[MMEM];
  for (int i=threadIdx.x;i<MMEM*DD;i+=128) wS[i] = Wc[(size_t)t*MMEM*DD + i];
  if (threadIdx.x < MMEM) bS[threadIdx.x] = bc[t*MMEM + threadIdx.x];
  __syncthreads();
  int e = blockIdx.x*128 + threadIdx.x; if (e >= cnt) return;
  int node = idx ? idx[(size_t)t*cnt + e] : e;
  float acc[MMEM];
  #pragma unroll
  for (int m=0;m<MMEM;m++) acc[m]=bS[m];
  const float* fr = feat + (size_t)node*DD;
  for (int d2=0; d2<DD; d2++){
    float v = fr[d2];
    #pragma unroll
    for (int m=0;m<MMEM;m++) acc[m] = fmaf(v, wS[m*DD+d2], acc[m]);
  }
  float* op = outc + ((size_t)t*cnt + e)*MMEM;
  #pragma unroll
  for (int m=0;m<MMEM;m++){ float v=acc[m]; op[m] = v>0.f ? v : 0.2f*v; }
}

// ---------- memory segment-sum gather: sAgg[n] = sum of msg rows ----------
__global__ void k_mem_gather(const int* __restrict__ rpT, const int* __restrict__ colT,
                             const float* __restrict__ msg, float* __restrict__ sAgg){
  int n = blockIdx.x*4 + (threadIdx.x >> 6);
  if (n >= NTOT) return;
  int lane = threadIdx.x & 63;
  int jb = rpT[n], je = rpT[n+1];
  float a0=0.f, a1=0.f;
  for (int j=jb;j<je;j++){
    const float* mp = msg + (size_t)colT[j]*128;
    a0 += mp[lane]; a1 += mp[lane+64];
  }
  sAgg[(size_t)n*128+lane] = a0;
  sAgg[(size_t)n*128+64+lane] = a1;
}

// ---------- memory LN: out = LN(s/max(cnt,1))*w + b + h_bias ----------
__global__ void k_memln(const float* __restrict__ s, const int* __restrict__ rpT,
                        const float* __restrict__ lw, const float* __restrict__ lb,
                        const float* __restrict__ hb, float* __restrict__ outp){
  int n = blockIdx.x, lane = threadIdx.x;
  float c = fmaxf((float)(rpT[n+1]-rpT[n]), 1.f);
  float x1 = s[(size_t)n*128+lane]/c, x2 = s[(size_t)n*128+64+lane]/c;
  float t = x1+x2;
  #pragma unroll
  for (int off=32;off;off>>=1) t += __shfl_xor(t,off);
  float mu = t * (1.f/128.f);
  float d1=x1-mu, d2=x2-mu;
  float v = d1*d1+d2*d2;
  #pragma unroll
  for (int off=32;off;off>>=1) v += __shfl_xor(v,off);
  float r = rsqrtf(v*(1.f/128.f) + 1e-5f);
  outp[(size_t)n*128+lane]    = d1*r*lw[lane]    + lb[lane]    + hb[lane];
  outp[(size_t)n*128+64+lane] = d2*r*lw[64+lane] + lb[64+lane] + hb[64+lane];
}

// ---------- finalize: feat_next = lrelu(mem) + trans ----------
__global__ void k_final_feat(const float* __restrict__ mo, const float* __restrict__ tr,
                             float* __restrict__ o, int n){
  int i = blockIdx.x*256+threadIdx.x; if (i>=n) return;
  float v = mo[i]; v = v>0.f ? v : 0.2f*v;
  o[i] = v + tr[i];
}

// ---------- final LN over 384-wide concat ----------
__global__ void k_final_ln(const float* __restrict__ emb, const float* __restrict__ f1,
                           const float* __restrict__ f2, const float* __restrict__ w,
                           const float* __restrict__ b, float* __restrict__ out){
  int n = blockIdx.x, t = threadIdx.x;
  __shared__ float red[4];
  float x0 = emb[(size_t)n*128+t];
  float x1 = f1[(size_t)n*128+t];
  float x2 = f2[(size_t)n*128+t];
  float s = x0+x1+x2;
  #pragma unroll
  for (int off=32;off;off>>=1) s += __shfl_xor(s,off);
  if ((t&63)==0) red[t>>6] = s;
  __syncthreads();
  float mu = (red[0]+red[1]) * (1.f/384.f);
  float d0=x0-mu, d1=x1-mu, d2=x2-mu;
  float v = d0*d0+d1*d1+d2*d2;
  #pragma unroll
  for (int off=32;off;off>>=1) v += __shfl_xor(v,off);
  if ((t&63)==0) red[2+(t>>6)] = v;
  __syncthreads();
  float var = (red[2]+red[3]) * (1.f/384.f);
  float r = rsqrtf(var + 1e-5f);
  size_t o = (size_t)n*384;
  out[o+t]     = d0*r*w[t]     + b[t];
  out[o+128+t] = d1*r*w[128+t] + b[128+t];
  out[o+256+t] = d2*r*w[256+t] + b[256+t];
}

extern "C" void kernel_launch(void* const* d_in, const int* in_sizes, int n_in,
                              void* d_out, int out_size, void* d_ws, size_t ws_size,
                              hipStream_t stream)
{
  const float* emb   = (const float*)d_in[0];
  const float* fcW   = (const float*)d_in[1];
  const float* attl  = (const float*)d_in[2];
  const float* attr  = (const float*)d_in[3];
  const float* gbias = (const float*)d_in[4];
  const float* projW = (const float*)d_in[5];
  const float* projB = (const float*)d_in[6];
  const float* relWc = (const float*)d_in[7];
  const float* relbc = (const float*)d_in[8];
  const float* relWw = (const float*)d_in[9];
  const float* nodWc = (const float*)d_in[10];
  const float* nodbc = (const float*)d_in[11];
  const float* nodWw = (const float*)d_in[12];
  const float* hbias = (const float*)d_in[13];
  const float* mlnw  = (const float*)d_in[14];
  const float* mlnb  = (const float*)d_in[15];
  const float* flnw  = (const float*)d_in[16];
  const float* flnb  = (const float*)d_in[17];
  const int*  srcU  = (const int*)d_in[18];
  const int*  dstI  = (const int*)d_in[19];
  const int*  eSrc  = (const int*)d_in[20];
  const int*  eDst  = (const int*)d_in[21];
  float* out = (float*)d_out;

  char* wp = (char*)d_ws;
  auto alloc = [&](size_t bytes)->void* {
    void* p = (void*)wp; wp += (bytes + 511) & ~(size_t)511; return p;
  };
  float* feat1 = (float*)alloc((size_t)NTOT*DD*4);
  float* feat2 = (float*)alloc((size_t)NTOT*DD*4);
  float* Fbuf  = (float*)alloc((size_t)NTOT*512*4);
  float* rst   = (float*)alloc((size_t)NTOT*512*4);
  float* trans = (float*)alloc((size_t)NTOT*DD*4);
  float* elF   = (float*)alloc((size_t)NTOT*4*4);
  float* erF   = (float*)alloc((size_t)NTOT*4*4);
  int* rpA  = (int*)alloc((size_t)(NUSER+1)*4);
  int* colA = (int*)alloc((size_t)EUI*4);
  int* rpB  = (int*)alloc((size_t)(NITEM+1)*4);
  int* colB = (int*)alloc((size_t)EUI*4);
  int* icnt = (int*)alloc((size_t)20000*4);
  int* icur = (int*)alloc((size_t)20000*4);
  int* rpT  = (int*)alloc((size_t)(NTOT+1)*4);
  int* colT = (int*)alloc((size_t)TT*ET*4);
  int* cntT = (int*)alloc((size_t)NTOT*4);
  int* icurT= (int*)alloc((size_t)NTOT*4);
  bf16* featb  = (bf16*)alloc((size_t)MP_N*DD*2);
  bf16* fcWb   = (bf16*)alloc((size_t)4*512*DD*2);
  bf16* projWb = (bf16*)alloc((size_t)4*DD*512*2);
  bf16* relWwb = (bf16*)alloc((size_t)10*DD*1024*2);
  bf16* nodWwb = (bf16*)alloc((size_t)2*DD*1024*2);
  // overlays:
  float* msgB = Fbuf;                                   // [T*ET x 128] fp32 (41 MB)
  bf16*  Aeff = (bf16*)(Fbuf + (size_t)TT*ET*128);      // [16000 x 1024] bf16 (33 MB)
  bf16*  Aeff2= (bf16*)Fbuf;                            // [MP_H x 1024] bf16 (41 MB, after msgB dead)
  float* sAgg   = rst;
  float* memO   = rst + (size_t)NTOT*DD;
  float* coefB  = rst + (size_t)2*NTOT*DD;
  float* ncoefB = coefB + (size_t)TT*ET*8;

  // ---- one-time: weight conversion/repack ----
  k_f2b<<<dim3((4*512*DD+255)/256),256,0,stream>>>(fcW, fcWb, 4*512*DD, 4*512*DD);
  k_f2b<<<dim3((4*DD*512+255)/256),256,0,stream>>>(projW, projWb, 4*DD*512, 4*DD*512);
  k_repack<<<dim3(512,10),256,0,stream>>>(relWw, relWwb);
  k_repack<<<dim3(512,2),256,0,stream>>>(nodWw, nodWwb);

  // ---- one-time: CSR builds ----
  hipMemsetAsync(icnt, 0, 20000*4, stream);
  hipMemsetAsync(icur, 0, 20000*4, stream);
  k_hist<<<dim3((EUI+255)/256),256,0,stream>>>(srcU, icnt, EUI);
  k_scan<<<dim3(1),1024,0,stream>>>(icnt, rpA, NUSER);
  k_csr_scatter<<<dim3((EUI+255)/256),256,0,stream>>>(dstI, srcU, NUSER, rpA, icur, colA, EUI);
  hipMemsetAsync(icnt, 0, 20000*4, stream);
  hipMemsetAsync(icur, 0, 20000*4, stream);
  k_hist<<<dim3((EUI+255)/256),256,0,stream>>>(dstI, icnt, EUI);
  k_scan<<<dim3(1),1024,0,stream>>>(icnt, rpB, NITEM);
  k_csr_scatter<<<dim3((EUI+255)/256),256,0,stream>>>(srcU, dstI, 0, rpB, icur, colB, EUI);
  hipMemsetAsync(cntT, 0, NTOT*4, stream);
  hipMemsetAsync(icurT, 0, NTOT*4, stream);
  k_hist<<<dim3((TT*ET+255)/256),256,0,stream>>>(eDst, cntT, TT*ET);
  k_scan<<<dim3(1),1024,0,stream>>>(cntT, rpT, NTOT);
  k_csr_scatter_eid<<<dim3((TT*ET+255)/256),256,0,stream>>>(eDst, rpT, icurT, colT, TT*ET);

  const float* feats[3] = {emb, feat1, feat2};
  for (int l=0; l<2; l++){
    const float* fin  = feats[l];
    float* fout = (float*)feats[l+1];

    // bf16 copy of features (padded rows zeroed)
    k_f2b<<<dim3((MP_N*DD+255)/256),256,0,stream>>>(fin, featb, NTOT*DD, MP_N*DD);

    for (int d=0; d<2; d++){
      // F = feat @ W^T : M=40000(pad 40064), N=512, K=128
      k_mfma_gemm<<<dim3(MP_N/128, 4),256,0,stream>>>(
          featb, fcWb + (size_t)(l*2+d)*512*DD, nullptr,
          Fbuf, 512, NTOT, DD, 0, 0);
      k_attn<<<dim3(NTOT),64,0,stream>>>(Fbuf,
          attl+(size_t)(l*2+d)*512, attr+(size_t)(l*2+d)*512, elF, erF);
      int dOff = (d==0) ? 0 : NUSER;
      const int* rp  = (d==0) ? rpA : rpB;
      const int* col = (d==0) ? colA : colB;
      k_gat_gather<<<dim3(20000),64,0,stream>>>(rp, col, elF, erF, Fbuf, rst, dOff, 20000);
      // rstb = bf16(elu(rst_half + gbias))  -> placed in rst's other (dead) half
      bf16* rstb = (bf16*)(rst + (size_t)(d==0 ? NUSER : 0)*512);
      k_rstb<<<dim3(MP_H),128,0,stream>>>(rst + (size_t)dOff*512,
                                          gbias+(size_t)(l*2+d)*512, rstb);
      // trans_half = elu(rstb @ projW^T + projB): M=20000, N=128, K=512
      k_mfma_gemm<<<dim3(MP_H/128, 1),256,0,stream>>>(
          rstb, projWb + (size_t)(l*2+d)*DD*512, projB+(size_t)(l*2+d)*DD,
          trans + (size_t)dOff*DD, DD, 20000, 512, 1, 0);
    }

    // ---- memory layer ----
    k_coef<<<dim3((ET+127)/128, TT),128,0,stream>>>(fin, eDst,
        relWc+(size_t)l*TT*MMEM*DD, relbc+(size_t)l*TT*MMEM, coefB, ET);
    for (int t=0; t<TT; t++){
      k_aeff_rel<<<dim3(ET/4),256,0,stream>>>(fin, eSrc+(size_t)t*ET,
          coefB+(size_t)t*ET*8, Aeff, ET);
      k_mfma_gemm<<<dim3(ET/128, 1),256,0,stream>>>(
          Aeff, relWwb + (size_t)(l*TT+t)*DD*1024, nullptr,
          msgB + (size_t)t*ET*128, DD, ET, 1024, 0, 0);
    }
    k_mem_gather<<<dim3(NTOT/4),256,0,stream>>>(rpT, colT, msgB, sAgg);
    k_memln<<<dim3(NTOT),64,0,stream>>>(sAgg, rpT, mlnw+(size_t)l*DD, mlnb+(size_t)l*DD,
                                        hbias+(size_t)l*DD, memO);
    k_coef<<<dim3((NTOT+127)/128, 1),128,0,stream>>>(fin, nullptr,
        nodWc+(size_t)l*MMEM*DD, nodbc+(size_t)l*MMEM, ncoefB, NTOT);
    for (int c=0; c<2; c++){
      k_aeff_node<<<dim3(MP_H/4),256,0,stream>>>(fin, ncoefB, Aeff2, c*20000);
      k_mfma_gemm<<<dim3(MP_H/128, 1),256,0,stream>>>(
          Aeff2, nodWwb + (size_t)l*DD*1024, nullptr,
          memO + (size_t)c*20000*DD, DD, 20000, 1024, 0, 1);
    }
    k_final_feat<<<dim3((NTOT*DD+255)/256),256,0,stream>>>(memO, trans, fout, NTOT*DD);
  }

  k_final_ln<<<dim3(NTOT),128,0,stream>>>(emb, feat1, feat2, flnw, flnb, out);
}

// Round 5
// 1053.052 us; speedup vs baseline: 7.2673x; 1.4801x over previous
//
#include <hip/hip_runtime.h>
#include <hip/hip_bf16.h>
#include <math.h>

typedef __hip_bfloat16 bf16;

#define NUSER 20000
#define NITEM 20000
#define NTOT  40000
#define DD    128
#define HH    4
#define TT    5
#define MMEM  8
#define EUI   40000
#define ET    16000

#define MP_N  40064   // NTOT padded to 128
#define MP_H  20096   // 20000 padded to 128

typedef __attribute__((ext_vector_type(8))) short short8;
typedef __attribute__((ext_vector_type(4))) float f32x4;

__device__ __forceinline__ void gload16(const bf16* g, bf16* l){
  __builtin_amdgcn_global_load_lds(
      (const __attribute__((address_space(1))) unsigned int*)g,
      (__attribute__((address_space(3))) unsigned int*)l, 16, 0, 0);
}

// swizzled col-group (elements) for global_load_lds staging of a 32-col tile:
// lane l fetches global colgrp ((l&3) ^ ((l>>2)&3) ^ (l>>4)); LDS slot (R,p) then
// holds colgrp p ^ (R&3) ^ ((R>>2)&3), making b128 fragment reads 2-way (free).
__device__ __forceinline__ int stage_cg(int lane){
  return (((lane&3) ^ ((lane>>2)&3) ^ (lane>>4)) << 3);
}
__device__ __forceinline__ int read_pc8(int lm, int lq){
  return ((lq ^ (lm&3) ^ ((lm>>2)&3)) << 3);
}

// ================= MFMA bf16 GEMM: C = act(A @ B^T + bias) =================
// A: [Mp x K] bf16 row-major (rows >= M zero-padded); B: [N x K] bf16; K %32==0
// blockIdx.z batches: ptr += z*stride (element strides)
__global__ __launch_bounds__(256) void k_mfma_gemm(
    const bf16* __restrict__ A, const bf16* __restrict__ B,
    const float* __restrict__ bias, float* __restrict__ C,
    long Astr, long Bstr, long biasStr, long Cstr,
    int ldc, int M, int K, int act, int accum)
{
  A += (size_t)blockIdx.z*Astr; B += (size_t)blockIdx.z*Bstr;
  if (bias) bias += (size_t)blockIdx.z*biasStr;
  C += (size_t)blockIdx.z*Cstr;
  __shared__ bf16 As[128*32];
  __shared__ bf16 Bs[128*32];
  int tid = threadIdx.x;
  int wave = tid >> 6, lane = tid & 63;
  int r0 = blockIdx.x * 128, c0 = blockIdx.y * 128;
  int wm = (wave >> 1) * 64, wn = (wave & 1) * 64;
  f32x4 acc[4][4];
  #pragma unroll
  for (int i=0;i<4;i++)
    #pragma unroll
    for (int j=0;j<4;j++) acc[i][j] = (f32x4){0.f,0.f,0.f,0.f};

  int rq = lane >> 2;
  int cg = stage_cg(lane);
  const bf16* Ag = A + (size_t)(r0 + wave*32 + rq)*K + cg;
  const bf16* Bg = B + (size_t)(c0 + wave*32 + rq)*K + cg;
  bf16* AsW = As + wave*32*32;
  bf16* BsW = Bs + wave*32*32;
  int lm = lane & 15, lq = lane >> 4;
  int pc8 = read_pc8(lm, lq);
  const bf16* Ard = As + (wm + lm)*32 + pc8;
  const bf16* Brd = Bs + (wn + lm)*32 + pc8;

  for (int k0 = 0; k0 < K; k0 += 32){
    gload16(Ag + k0,            AsW);
    gload16(Ag + 16*K + k0,     AsW + 16*32);
    gload16(Bg + k0,            BsW);
    gload16(Bg + 16*K + k0,     BsW + 16*32);
    __syncthreads();
    short8 af[4], bfv[4];
    #pragma unroll
    for (int i=0;i<4;i++) af[i]  = *(const short8*)(Ard + i*16*32);
    #pragma unroll
    for (int j=0;j<4;j++) bfv[j] = *(const short8*)(Brd + j*16*32);
    #pragma unroll
    for (int i=0;i<4;i++)
      #pragma unroll
      for (int j=0;j<4;j++)
        acc[i][j] = __builtin_amdgcn_mfma_f32_16x16x32_bf16(af[i], bfv[j], acc[i][j], 0, 0, 0);
    __syncthreads();
  }
  #pragma unroll
  for (int i=0;i<4;i++){
    #pragma unroll
    for (int j=0;j<4;j++){
      int c = c0 + wn + j*16 + lm;
      #pragma unroll
      for (int rg=0; rg<4; rg++){
        int r = r0 + wm + i*16 + lq*4 + rg;
        if (r < M){
          float v = acc[i][j][rg];
          if (bias) v += bias[c];
          if (act==1) v = v>0.f ? v : expm1f(v);
          float* cp = &C[(size_t)r*ldc + c];
          if (accum) *cp += v; else *cp = v;
        }
      }
    }
  }
}

// ====== fused memory GEMM: C[r,o] = sum_k coef[r,k>>7]*feat[src[r],k&127]*B[o,k]
// K=1024, N=128. feat tile staged once in LDS; coef applied as register scale.
// grid (Mp/128, nT). src==null -> identity gather.
__global__ __launch_bounds__(256) void k_memgemm(
    const float* __restrict__ feat, const int* __restrict__ src,
    const float* __restrict__ coef, const bf16* __restrict__ B,
    float* __restrict__ C,
    long srcStr, long coefStr, long Bstr, long Cstr,
    int Mvalid, int accum)
{
  __shared__ bf16 Af[128*136];
  __shared__ float cfS[128*8];
  __shared__ bf16 Bs[2][128*32];
  int t = blockIdx.y;
  const int*   srcT  = src ? src + (size_t)t*srcStr : nullptr;
  const float* coefT = coef + (size_t)t*coefStr;
  const bf16*  Bt    = B + (size_t)t*Bstr;
  float*       Ct    = C + (size_t)t*Cstr;
  int tid = threadIdx.x, wave = tid >> 6, lane = tid & 63;
  int r0 = blockIdx.x * 128;

  // ---- stage feat rows (bf16) + coef into LDS ----
  {
    int rL = tid >> 1, hf = tid & 1;
    int r = r0 + rL;
    bool valid = r < Mvalid;
    int s = valid ? (srcT ? srcT[r] : r) : 0;
    const float4* fp = (const float4*)(feat + (size_t)s*128 + hf*64);
    bf16* ap = Af + rL*136 + hf*64;
    #pragma unroll
    for (int q=0;q<16;q++){
      float4 v = fp[q];
      __hip_bfloat162 p0 = __float22bfloat162_rn(make_float2(v.x, v.y));
      __hip_bfloat162 p1 = __float22bfloat162_rn(make_float2(v.z, v.w));
      *(__hip_bfloat162*)(ap + q*4)     = p0;
      *(__hip_bfloat162*)(ap + q*4 + 2) = p1;
    }
    if (hf == 0){
      float4 c0v, c1v;
      if (valid){
        c0v = *(const float4*)(coefT + (size_t)r*8);
        c1v = *(const float4*)(coefT + (size_t)r*8 + 4);
      } else { c0v = make_float4(0.f,0.f,0.f,0.f); c1v = c0v; }
      *(float4*)(cfS + rL*8)     = c0v;
      *(float4*)(cfS + rL*8 + 4) = c1v;
    }
  }

  int rq = lane >> 2;
  int cg = stage_cg(lane);
  const bf16* Bg0 = Bt + (size_t)(wave*32 + rq)*1024 + cg;
  const bf16* Bg1 = Bt + (size_t)(wave*32 + 16 + rq)*1024 + cg;

  int wm = (wave >> 1) * 64, wn = (wave & 1) * 64;
  int lm = lane & 15, lq = lane >> 4;
  int pc8 = read_pc8(lm, lq);

  f32x4 acc[4][4];
  #pragma unroll
  for (int i=0;i<4;i++)
    #pragma unroll
    for (int j=0;j<4;j++) acc[i][j] = (f32x4){0.f,0.f,0.f,0.f};

  // prefetch first B tile
  {
    bf16* d = Bs[0] + wave*1024;
    gload16(Bg0, d);
    gload16(Bg1, d + 512);
  }
  __syncthreads();   // also covers Af/cfS staging

  int buf = 0;
  for (int m = 0; m < 8; m++){
    float cfr[4];
    #pragma unroll
    for (int i=0;i<4;i++) cfr[i] = cfS[(wm + i*16 + lm)*8 + m];
    #pragma unroll
    for (int ic = 0; ic < 4; ic++){
      int kk = m*4 + ic;
      if (kk + 1 < 32){
        int k1 = (kk + 1) * 32;
        bf16* d = Bs[buf^1] + wave*1024;
        gload16(Bg0 + k1, d);
        gload16(Bg1 + k1, d + 512);
      }
      short8 af[4], bfv[4];
      #pragma unroll
      for (int i=0;i<4;i++){
        short8 raw = *(const short8*)(Af + (size_t)(wm + i*16 + lm)*136 + ic*32 + lq*8);
        union { short8 s; unsigned u[4]; } U, V;
        U.s = raw;
        float c = cfr[i];
        #pragma unroll
        for (int p=0;p<4;p++){
          float lo = __uint_as_float(U.u[p] << 16) * c;
          float hi = __uint_as_float(U.u[p] & 0xffff0000u) * c;
          __hip_bfloat162 pk = __float22bfloat162_rn(make_float2(lo, hi));
          V.u[p] = *(unsigned*)&pk;
        }
        af[i] = V.s;
      }
      #pragma unroll
      for (int j=0;j<4;j++)
        bfv[j] = *(const short8*)(Bs[buf] + (wn + lm + j*16)*32 + pc8);
      #pragma unroll
      for (int i=0;i<4;i++)
        #pragma unroll
        for (int j=0;j<4;j++)
          acc[i][j] = __builtin_amdgcn_mfma_f32_16x16x32_bf16(af[i], bfv[j], acc[i][j], 0, 0, 0);
      __syncthreads();
      buf ^= 1;
    }
  }
  #pragma unroll
  for (int i=0;i<4;i++){
    #pragma unroll
    for (int j=0;j<4;j++){
      int c = wn + j*16 + lm;
      #pragma unroll
      for (int rg=0; rg<4; rg++){
        int r = r0 + wm + i*16 + lq*4 + rg;
        if (r < Mvalid){
          float* cp = &Ct[(size_t)r*128 + c];
          if (accum) *cp += acc[i][j][rg]; else *cp = acc[i][j][rg];
        }
      }
    }
  }
}

// ---------- fp32 -> bf16 with zero pad ----------
__global__ void k_f2b(const float* __restrict__ in, bf16* __restrict__ o, int nv, int nt){
  int i = blockIdx.x*256 + threadIdx.x;
  if (i < nt) o[i] = __float2bfloat16(i < nv ? in[i] : 0.f);
}

// ---------- repack Ww (M,Do,Di) -> B^T [Do x (M*Di)] bf16, per slice ----------
__global__ void k_repack(const float* __restrict__ in, bf16* __restrict__ o){
  int s = blockIdx.y;
  int g = blockIdx.x*256 + threadIdx.x;          // g = m*16384 + od*128 + i
  int m = g >> 14, od = (g >> 7) & 127, i = g & 127;
  o[(size_t)s*131072 + (size_t)od*1024 + m*128 + i] = __float2bfloat16(in[(size_t)s*131072 + g]);
}

// ---------- rstb = bf16(elu(rst_row + gbias)), rows padded to MP_H ----------
__global__ void k_rstb(const float* __restrict__ rst, const float* __restrict__ gb,
                       bf16* __restrict__ o){
  int r = blockIdx.x, t = threadIdx.x;
  int k = t*4;
  bf16* op = o + (size_t)r*512 + k;
  if (r < 20000){
    const float* ip = rst + (size_t)r*512 + k;
    #pragma unroll
    for (int q=0;q<4;q++){
      float v = ip[q] + gb[k+q];
      v = v>0.f ? v : expm1f(v);
      op[q] = __float2bfloat16(v);
    }
  } else {
    #pragma unroll
    for (int q=0;q<4;q++) op[q] = __float2bfloat16(0.f);
  }
}

// ---------- attention dot products ----------
__global__ void k_attn(const float* __restrict__ F, const float* __restrict__ al,
                       const float* __restrict__ ar, float* __restrict__ el, float* __restrict__ er){
  int n = blockIdx.x, lane = threadIdx.x;
  const float* row = F + (size_t)n*512;
  #pragma unroll
  for (int h=0;h<HH;h++){
    float x1 = row[h*128+lane], x2 = row[h*128+64+lane];
    float vl = x1*al[h*128+lane] + x2*al[h*128+64+lane];
    float vr = x1*ar[h*128+lane] + x2*ar[h*128+64+lane];
    #pragma unroll
    for (int off=32;off;off>>=1){ vl += __shfl_xor(vl,off); vr += __shfl_xor(vr,off); }
    if (lane==0){ el[n*4+h]=vl; er[n*4+h]=vr; }
  }
}

// ---------- CSR build ----------
__global__ void k_hist(const int* __restrict__ dIdx, int* __restrict__ cnt, int E){
  int e = blockIdx.x*256+threadIdx.x;
  if (e<E) atomicAdd(&cnt[dIdx[e]], 1);
}

__global__ __launch_bounds__(1024) void k_scan(const int* __restrict__ in,
                                               int* __restrict__ out, int n){
  __shared__ int wsum[16];
  __shared__ int carry;
  int tidx = threadIdx.x, lane = tidx & 63, w = tidx >> 6;
  if (tidx == 0) carry = 0;
  __syncthreads();
  for (int base = 0; base < n; base += 1024){
    int i = base + tidx;
    int v = (i < n) ? in[i] : 0;
    int x = v;
    #pragma unroll
    for (int off = 1; off < 64; off <<= 1){
      int t = __shfl_up(x, off);
      if (lane >= off) x += t;
    }
    if (lane == 63) wsum[w] = x;
    __syncthreads();
    if (w == 0 && lane < 16){
      int t = wsum[lane];
      #pragma unroll
      for (int off=1; off<16; off<<=1){
        int u = __shfl_up(t, off, 16);
        if (lane >= off) t += u;
      }
      wsum[lane] = t;
    }
    __syncthreads();
    int woff = (w == 0) ? 0 : wsum[w-1];
    int excl = carry + woff + x - v;
    if (i < n) out[i] = excl;
    __syncthreads();
    if (tidx == 1023) carry = carry + wsum[15];
    __syncthreads();
  }
  if (tidx == 0) out[n] = carry;
}

__global__ void k_csr_scatter(const int* __restrict__ sIdx, const int* __restrict__ dIdx,
                              int sOff, const int* __restrict__ rowptr,
                              int* __restrict__ cursor, int* __restrict__ col, int E){
  int e = blockIdx.x*256+threadIdx.x; if (e>=E) return;
  int d = dIdx[e];
  int pos = rowptr[d] + atomicAdd(&cursor[d], 1);
  col[pos] = sIdx[e] + sOff;
}

__global__ void k_csr_scatter_eid(const int* __restrict__ dIdx, const int* __restrict__ rowptr,
                                  int* __restrict__ cursor, int* __restrict__ col, int E){
  int e = blockIdx.x*256+threadIdx.x; if (e>=E) return;
  int d = dIdx[e];
  int pos = rowptr[d] + atomicAdd(&cursor[d], 1);
  col[pos] = e;
}

// ---------- fused GAT aggregation: online softmax + gather, 1 wave/dst ----------
// writes rows 0..n_dst-1 (direction-local); dOff only offsets the er index.
__global__ __launch_bounds__(64) void k_gat_gather(
    const int* __restrict__ rowptr, const int* __restrict__ col,
    const float* __restrict__ el, const float* __restrict__ er,
    const float* __restrict__ F, float* __restrict__ rst,
    int dOff, int n_dst)
{
  int dl = blockIdx.x;
  int dn = dl + dOff;
  int lane = threadIdx.x;
  int h = lane >> 4;
  int off = (lane & 15) << 3;
  float erh = er[dn*4 + h];
  float m = -INFINITY, den = 0.f;
  float acc[8];
  #pragma unroll
  for (int i=0;i<8;i++) acc[i]=0.f;
  int jb = rowptr[dl], je = rowptr[dl+1];
  for (int j=jb; j<je; j++){
    int s = col[j];
    float e = el[s*4+h] + erh;
    e = e > 0.f ? e : 0.2f*e;
    float mn = fmaxf(m, e);
    float sc = __expf(m - mn);
    float wj = __expf(e - mn);
    den = den*sc + wj;
    m = mn;
    const float4* fp = (const float4*)(F + (size_t)s*512 + h*128 + off);
    float4 f0 = fp[0], f1 = fp[1];
    acc[0]=acc[0]*sc + wj*f0.x; acc[1]=acc[1]*sc + wj*f0.y;
    acc[2]=acc[2]*sc + wj*f0.z; acc[3]=acc[3]*sc + wj*f0.w;
    acc[4]=acc[4]*sc + wj*f1.x; acc[5]=acc[5]*sc + wj*f1.y;
    acc[6]=acc[6]*sc + wj*f1.z; acc[7]=acc[7]*sc + wj*f1.w;
  }
  float inv = den > 0.f ? 1.f/den : 0.f;
  float* rp = rst + (size_t)dl*512 + h*128 + off;
  ((float4*)rp)[0] = make_float4(acc[0]*inv, acc[1]*inv, acc[2]*inv, acc[3]*inv);
  ((float4*)rp)[1] = make_float4(acc[4]*inv, acc[5]*inv, acc[6]*inv, acc[7]*inv);
}

// ---------- coef / ncoef: lrelu(x @ Wc^T + bc), M=8 outputs ----------
__global__ void k_coef(const float* __restrict__ feat, const int* __restrict__ idx,
                       const float* __restrict__ Wc, const float* __restrict__ bc,
                       float* __restrict__ outc, int cnt){
  int t = blockIdx.y;
  __shared__ float wS[MMEM*DD];
  __shared__ float bS[MMEM];
  for (int i=threadIdx.x;i<MMEM*DD;i+=128) wS[i] = Wc[(size_t)t*MMEM*DD + i];
  if (threadIdx.x < MMEM) bS[threadIdx.x] = bc[t*MMEM + threadIdx.x];
  __syncthreads();
  int e = blockIdx.x*128 + threadIdx.x; if (e >= cnt) return;
  int node = idx ? idx[(size_t)t*cnt + e] : e;
  float acc[MMEM];
  #pragma unroll
  for (int m=0;m<MMEM;m++) acc[m]=bS[m];
  const float* fr = feat + (size_t)node*DD;
  for (int d2=0; d2<DD; d2++){
    float v = fr[d2];
    #pragma unroll
    for (int m=0;m<MMEM;m++) acc[m] = fmaf(v, wS[m*DD+d2], acc[m]);
  }
  float* op = outc + ((size_t)t*cnt + e)*MMEM;
  #pragma unroll
  for (int m=0;m<MMEM;m++){ float v=acc[m]; op[m] = v>0.f ? v : 0.2f*v; }
}

// ---------- memory segment-sum gather ----------
__global__ void k_mem_gather(const int* __restrict__ rpT, const int* __restrict__ colT,
                             const float* __restrict__ msg, float* __restrict__ sAgg){
  int n = blockIdx.x*4 + (threadIdx.x >> 6);
  if (n >= NTOT) return;
  int lane = threadIdx.x & 63;
  int jb = rpT[n], je = rpT[n+1];
  float a0=0.f, a1=0.f;
  for (int j=jb;j<je;j++){
    const float* mp = msg + (size_t)colT[j]*128;
    a0 += mp[lane]; a1 += mp[lane+64];
  }
  sAgg[(size_t)n*128+lane] = a0;
  sAgg[(size_t)n*128+64+lane] = a1;
}

// ---------- memory LN ----------
__global__ void k_memln(const float* __restrict__ s, const int* __restrict__ rpT,
                        const float* __restrict__ lw, const float* __restrict__ lb,
                        const float* __restrict__ hb, float* __restrict__ outp){
  int n = blockIdx.x, lane = threadIdx.x;
  float c = fmaxf((float)(rpT[n+1]-rpT[n]), 1.f);
  float x1 = s[(size_t)n*128+lane]/c, x2 = s[(size_t)n*128+64+lane]/c;
  float t = x1+x2;
  #pragma unroll
  for (int off=32;off;off>>=1) t += __shfl_xor(t,off);
  float mu = t * (1.f/128.f);
  float d1=x1-mu, d2=x2-mu;
  float v = d1*d1+d2*d2;
  #pragma unroll
  for (int off=32;off;off>>=1) v += __shfl_xor(v,off);
  float r = rsqrtf(v*(1.f/128.f) + 1e-5f);
  outp[(size_t)n*128+lane]    = d1*r*lw[lane]    + lb[lane]    + hb[lane];
  outp[(size_t)n*128+64+lane] = d2*r*lw[64+lane] + lb[64+lane] + hb[64+lane];
}

// ---------- finalize ----------
__global__ void k_final_feat(const float* __restrict__ mo, const float* __restrict__ tr,
                             float* __restrict__ o, int n){
  int i = blockIdx.x*256+threadIdx.x; if (i>=n) return;
  float v = mo[i]; v = v>0.f ? v : 0.2f*v;
  o[i] = v + tr[i];
}

// ---------- final LN over 384-wide concat ----------
__global__ void k_final_ln(const float* __restrict__ emb, const float* __restrict__ f1,
                           const float* __restrict__ f2, const float* __restrict__ w,
                           const float* __restrict__ b, float* __restrict__ out){
  int n = blockIdx.x, t = threadIdx.x;
  __shared__ float red[4];
  float x0 = emb[(size_t)n*128+t];
  float x1 = f1[(size_t)n*128+t];
  float x2 = f2[(size_t)n*128+t];
  float s = x0+x1+x2;
  #pragma unroll
  for (int off=32;off;off>>=1) s += __shfl_xor(s,off);
  if ((t&63)==0) red[t>>6] = s;
  __syncthreads();
  float mu = (red[0]+red[1]) * (1.f/384.f);
  float d0=x0-mu, d1=x1-mu, d2=x2-mu;
  float v = d0*d0+d1*d1+d2*d2;
  #pragma unroll
  for (int off=32;off;off>>=1) v += __shfl_xor(v,off);
  if ((t&63)==0) red[2+(t>>6)] = v;
  __syncthreads();
  float var = (red[2]+red[3]) * (1.f/384.f);
  float r = rsqrtf(var + 1e-5f);
  size_t o = (size_t)n*384;
  out[o+t]     = d0*r*w[t]     + b[t];
  out[o+128+t] = d1*r*w[128+t] + b[128+t];
  out[o+256+t] = d2*r*w[256+t] + b[256+t];
}

extern "C" void kernel_launch(void* const* d_in, const int* in_sizes, int n_in,
                              void* d_out, int out_size, void* d_ws, size_t ws_size,
                              hipStream_t stream)
{
  const float* emb   = (const float*)d_in[0];
  const float* fcW   = (const float*)d_in[1];
  const float* attl  = (const float*)d_in[2];
  const float* attr  = (const float*)d_in[3];
  const float* gbias = (const float*)d_in[4];
  const float* projW = (const float*)d_in[5];
  const float* projB = (const float*)d_in[6];
  const float* relWc = (const float*)d_in[7];
  const float* relbc = (const float*)d_in[8];
  const float* relWw = (const float*)d_in[9];
  const float* nodWc = (const float*)d_in[10];
  const float* nodbc = (const float*)d_in[11];
  const float* nodWw = (const float*)d_in[12];
  const float* hbias = (const float*)d_in[13];
  const float* mlnw  = (const float*)d_in[14];
  const float* mlnb  = (const float*)d_in[15];
  const float* flnw  = (const float*)d_in[16];
  const float* flnb  = (const float*)d_in[17];
  const int*  srcU  = (const int*)d_in[18];
  const int*  dstI  = (const int*)d_in[19];
  const int*  eSrc  = (const int*)d_in[20];
  const int*  eDst  = (const int*)d_in[21];
  float* out = (float*)d_out;

  char* wp = (char*)d_ws;
  auto alloc = [&](size_t bytes)->void* {
    void* p = (void*)wp; wp += (bytes + 511) & ~(size_t)511; return p;
  };
  float* feat1 = (float*)alloc((size_t)NTOT*DD*4);
  float* feat2 = (float*)alloc((size_t)NTOT*DD*4);
  float* Fbuf  = (float*)alloc((size_t)NTOT*512*4);
  float* rst   = (float*)alloc((size_t)(NTOT+256)*512*4);
  float* trans = (float*)alloc((size_t)NTOT*DD*4);
  float* elF   = (float*)alloc((size_t)NTOT*4*4);
  float* erF   = (float*)alloc((size_t)NTOT*4*4);
  int* rpA  = (int*)alloc((size_t)(NUSER+1)*4);
  int* colA = (int*)alloc((size_t)EUI*4);
  int* rpB  = (int*)alloc((size_t)(NITEM+1)*4);
  int* colB = (int*)alloc((size_t)EUI*4);
  int* icnt = (int*)alloc((size_t)20000*4);
  int* icur = (int*)alloc((size_t)20000*4);
  int* rpT  = (int*)alloc((size_t)(NTOT+1)*4);
  int* colT = (int*)alloc((size_t)TT*ET*4);
  int* cntT = (int*)alloc((size_t)NTOT*4);
  int* icurT= (int*)alloc((size_t)NTOT*4);
  bf16* featb  = (bf16*)alloc((size_t)MP_N*DD*2);
  bf16* fcWb   = (bf16*)alloc((size_t)4*512*DD*2);
  bf16* projWb = (bf16*)alloc((size_t)4*DD*512*2);
  bf16* relWwb = (bf16*)alloc((size_t)10*DD*1024*2);
  bf16* nodWwb = (bf16*)alloc((size_t)2*DD*1024*2);
  // overlays:
  // gather always writes rst rows [0,20000); rstb (bf16) lives above row 20000
  bf16* rstb0 = (bf16*)(rst + (size_t)20000*512);
  bf16* rstb1 = rstb0 + (size_t)MP_H*512;
  // memory layer: sAgg/memO in rst rows [0,20000) region (after proj consumed rstb? no —
  // sAgg+memO = 40.96 MB = exactly rows [0,20000) fp32, does not touch rstb region)
  float* sAgg   = rst;
  float* memO   = rst + (size_t)NTOT*DD;
  // msgB + coefs in Fbuf (F dead during memory layer)
  float* msgB   = Fbuf;                               // 5*ET*128 fp32
  float* coefB  = Fbuf + (size_t)TT*ET*128;           // 5*ET*8
  float* ncoefB = coefB + (size_t)TT*ET*8;            // NTOT*8

  // ---- one-time: weight conversion/repack ----
  k_f2b<<<dim3((4*512*DD+255)/256),256,0,stream>>>(fcW, fcWb, 4*512*DD, 4*512*DD);
  k_f2b<<<dim3((4*DD*512+255)/256),256,0,stream>>>(projW, projWb, 4*DD*512, 4*DD*512);
  k_repack<<<dim3(512,10),256,0,stream>>>(relWw, relWwb);
  k_repack<<<dim3(512,2),256,0,stream>>>(nodWw, nodWwb);

  // ---- one-time: CSR builds ----
  hipMemsetAsync(icnt, 0, 20000*4, stream);
  hipMemsetAsync(icur, 0, 20000*4, stream);
  k_hist<<<dim3((EUI+255)/256),256,0,stream>>>(srcU, icnt, EUI);
  k_scan<<<dim3(1),1024,0,stream>>>(icnt, rpA, NUSER);
  k_csr_scatter<<<dim3((EUI+255)/256),256,0,stream>>>(dstI, srcU, NUSER, rpA, icur, colA, EUI);
  hipMemsetAsync(icnt, 0, 20000*4, stream);
  hipMemsetAsync(icur, 0, 20000*4, stream);
  k_hist<<<dim3((EUI+255)/256),256,0,stream>>>(dstI, icnt, EUI);
  k_scan<<<dim3(1),1024,0,stream>>>(icnt, rpB, NITEM);
  k_csr_scatter<<<dim3((EUI+255)/256),256,0,stream>>>(srcU, dstI, 0, rpB, icur, colB, EUI);
  hipMemsetAsync(cntT, 0, NTOT*4, stream);
  hipMemsetAsync(icurT, 0, NTOT*4, stream);
  k_hist<<<dim3((TT*ET+255)/256),256,0,stream>>>(eDst, cntT, TT*ET);
  k_scan<<<dim3(1),1024,0,stream>>>(cntT, rpT, NTOT);
  k_csr_scatter_eid<<<dim3((TT*ET+255)/256),256,0,stream>>>(eDst, rpT, icurT, colT, TT*ET);

  const float* feats[3] = {emb, feat1, feat2};
  for (int l=0; l<2; l++){
    const float* fin  = feats[l];
    float* fout = (float*)feats[l+1];

    k_f2b<<<dim3((MP_N*DD+255)/256),256,0,stream>>>(fin, featb, NTOT*DD, MP_N*DD);

    for (int d=0; d<2; d++){
      // F = feat @ W^T : M=40000(pad), N=512, K=128
      k_mfma_gemm<<<dim3(MP_N/128, 4, 1),256,0,stream>>>(
          featb, fcWb + (size_t)(l*2+d)*512*DD, nullptr, Fbuf,
          0,0,0,0, 512, NTOT, DD, 0, 0);
      k_attn<<<dim3(NTOT),64,0,stream>>>(Fbuf,
          attl+(size_t)(l*2+d)*512, attr+(size_t)(l*2+d)*512, elF, erF);
      int dOff = (d==0) ? 0 : NUSER;
      const int* rp  = (d==0) ? rpA : rpB;
      const int* col = (d==0) ? colA : colB;
      k_gat_gather<<<dim3(20000),64,0,stream>>>(rp, col, elF, erF, Fbuf, rst, dOff, 20000);
      k_rstb<<<dim3(MP_H),128,0,stream>>>(rst, gbias+(size_t)(l*2+d)*512,
                                          (d==0) ? rstb0 : rstb1);
    }
    // proj both directions in one dispatch: M=20000, N=128, K=512
    k_mfma_gemm<<<dim3(MP_H/128, 1, 2),256,0,stream>>>(
        rstb0, projWb + (size_t)(l*2)*DD*512, projB + (size_t)(l*2)*DD, trans,
        (long)MP_H*512, (long)DD*512, (long)DD, (long)20000*DD,
        DD, 20000, 512, 1, 0);

    // ---- memory layer ----
    k_coef<<<dim3((ET+127)/128, TT),128,0,stream>>>(fin, eDst,
        relWc+(size_t)l*TT*MMEM*DD, relbc+(size_t)l*TT*MMEM, coefB, ET);
    k_memgemm<<<dim3(ET/128, TT),256,0,stream>>>(
        fin, eSrc, coefB, relWwb + (size_t)l*TT*DD*1024, msgB,
        (long)ET, (long)ET*8, (long)DD*1024, (long)ET*128, ET, 0);
    k_mem_gather<<<dim3(NTOT/4),256,0,stream>>>(rpT, colT, msgB, sAgg);
    k_memln<<<dim3(NTOT),64,0,stream>>>(sAgg, rpT, mlnw+(size_t)l*DD, mlnb+(size_t)l*DD,
                                        hbias+(size_t)l*DD, memO);
    k_coef<<<dim3((NTOT+127)/128, 1),128,0,stream>>>(fin, nullptr,
        nodWc+(size_t)l*MMEM*DD, nodbc+(size_t)l*MMEM, ncoefB, NTOT);
    k_memgemm<<<dim3(MP_N/128, 1),256,0,stream>>>(
        fin, nullptr, ncoefB, nodWwb + (size_t)l*DD*1024, memO,
        0, 0, 0, 0, NTOT, 1);
    k_final_feat<<<dim3((NTOT*DD+255)/256),256,0,stream>>>(memO, trans, fout, NTOT*DD);
  }

  k_final_ln<<<dim3(NTOT),128,0,stream>>>(emb, feat1, feat2, flnw, flnb, out);
}

// Round 6
// 950.816 us; speedup vs baseline: 8.0487x; 1.1075x over previous
//
#include <hip/hip_runtime.h>
#include <hip/hip_bf16.h>
#include <math.h>

typedef __hip_bfloat16 bf16;

#define NUSER 20000
#define NITEM 20000
#define NTOT  40000
#define DD    128
#define HH    4
#define TT    5
#define MMEM  8
#define EUI   40000
#define ET    16000

#define MP_N  40064   // NTOT padded to 128
#define MP_H  20096   // 20000 padded to 128

typedef __attribute__((ext_vector_type(8))) short short8;
typedef __attribute__((ext_vector_type(4))) float f32x4;

__device__ __forceinline__ void gload16(const bf16* g, bf16* l){
  __builtin_amdgcn_global_load_lds(
      (const __attribute__((address_space(1))) unsigned int*)g,
      (__attribute__((address_space(3))) unsigned int*)l, 16, 0, 0);
}
__device__ __forceinline__ float bu2f_lo(unsigned u){ return __uint_as_float(u << 16); }
__device__ __forceinline__ float bu2f_hi(unsigned u){ return __uint_as_float(u & 0xffff0000u); }

// swizzle helpers for global_load_lds staging of 32-col bf16 tiles (stride 32)
__device__ __forceinline__ int stage_cg(int lane){
  return (((lane&3) ^ ((lane>>2)&3) ^ (lane>>4)) << 3);
}
__device__ __forceinline__ int read_pc8(int lm, int lq){
  return ((lq ^ (lm&3) ^ ((lm>>2)&3)) << 3);
}

// ================= generic MFMA bf16 GEMM (used for proj) =================
// C = act(A @ B^T + bias); A:[Mp x K] bf16 (pad rows zero); B:[N x K] bf16; K%32==0
__global__ __launch_bounds__(256) void k_mfma_gemm(
    const bf16* __restrict__ A, const bf16* __restrict__ B,
    const float* __restrict__ bias, float* __restrict__ C,
    long Astr, long Bstr, long biasStr, long Cstr,
    int ldc, int M, int K, int act, int accum)
{
  A += (size_t)blockIdx.z*Astr; B += (size_t)blockIdx.z*Bstr;
  if (bias) bias += (size_t)blockIdx.z*biasStr;
  C += (size_t)blockIdx.z*Cstr;
  __shared__ bf16 As[128*32];
  __shared__ bf16 Bs[128*32];
  int tid = threadIdx.x;
  int wave = tid >> 6, lane = tid & 63;
  int r0 = blockIdx.x * 128, c0 = blockIdx.y * 128;
  int wm = (wave >> 1) * 64, wn = (wave & 1) * 64;
  f32x4 acc[4][4];
  #pragma unroll
  for (int i=0;i<4;i++)
    #pragma unroll
    for (int j=0;j<4;j++) acc[i][j] = (f32x4){0.f,0.f,0.f,0.f};

  int rq = lane >> 2;
  int cg = stage_cg(lane);
  const bf16* Ag = A + (size_t)(r0 + wave*32 + rq)*K + cg;
  const bf16* Bg = B + (size_t)(c0 + wave*32 + rq)*K + cg;
  bf16* AsW = As + wave*32*32;
  bf16* BsW = Bs + wave*32*32;
  int lm = lane & 15, lq = lane >> 4;
  int pc8 = read_pc8(lm, lq);
  const bf16* Ard = As + (wm + lm)*32 + pc8;
  const bf16* Brd = Bs + (wn + lm)*32 + pc8;

  for (int k0 = 0; k0 < K; k0 += 32){
    gload16(Ag + k0,            AsW);
    gload16(Ag + 16*K + k0,     AsW + 16*32);
    gload16(Bg + k0,            BsW);
    gload16(Bg + 16*K + k0,     BsW + 16*32);
    __syncthreads();
    short8 af[4], bfv[4];
    #pragma unroll
    for (int i=0;i<4;i++) af[i]  = *(const short8*)(Ard + i*16*32);
    #pragma unroll
    for (int j=0;j<4;j++) bfv[j] = *(const short8*)(Brd + j*16*32);
    #pragma unroll
    for (int i=0;i<4;i++)
      #pragma unroll
      for (int j=0;j<4;j++)
        acc[i][j] = __builtin_amdgcn_mfma_f32_16x16x32_bf16(af[i], bfv[j], acc[i][j], 0, 0, 0);
    __syncthreads();
  }
  #pragma unroll
  for (int i=0;i<4;i++){
    #pragma unroll
    for (int j=0;j<4;j++){
      int c = c0 + wn + j*16 + lm;
      #pragma unroll
      for (int rg=0; rg<4; rg++){
        int r = r0 + wm + i*16 + lq*4 + rg;
        if (r < M){
          float v = acc[i][j][rg];
          if (bias) v += bias[c];
          if (act==1) v = v>0.f ? v : expm1f(v);
          float* cp = &C[(size_t)r*ldc + c];
          if (accum) *cp += v; else *cp = v;
        }
      }
    }
  }
}

// ============ fc GEMM fused with attention dots, bf16 F output ============
// F[r, h*128+c] = (featb @ W^T); el/er[r,h] = sum_c F*al / F*ar
// grid (MP_N/128, 4 heads); A:[MP_N x 128] bf16; B:[512 x 128] bf16 (head h rows h*128..)
__global__ __launch_bounds__(256) void k_fc_gemm(
    const bf16* __restrict__ A, const bf16* __restrict__ B,
    bf16* __restrict__ Fb, const float* __restrict__ al, const float* __restrict__ ar,
    float* __restrict__ el, float* __restrict__ er, int M)
{
  __shared__ bf16 As[128*32];
  __shared__ bf16 Bs[128*32];
  __shared__ float redE[2][2][128];   // [el|er][wn-half][row]
  int tid = threadIdx.x;
  int wave = tid >> 6, lane = tid & 63;
  int h = blockIdx.y;
  int r0 = blockIdx.x * 128;
  int wm = (wave >> 1) * 64, wn = (wave & 1) * 64;
  f32x4 acc[4][4];
  #pragma unroll
  for (int i=0;i<4;i++)
    #pragma unroll
    for (int j=0;j<4;j++) acc[i][j] = (f32x4){0.f,0.f,0.f,0.f};

  int rq = lane >> 2;
  int cg = stage_cg(lane);
  const bf16* Ag = A + (size_t)(r0 + wave*32 + rq)*128 + cg;
  const bf16* Bg = B + (size_t)(h*128 + wave*32 + rq)*128 + cg;
  bf16* AsW = As + wave*32*32;
  bf16* BsW = Bs + wave*32*32;
  int lm = lane & 15, lq = lane >> 4;
  int pc8 = read_pc8(lm, lq);
  const bf16* Ard = As + (wm + lm)*32 + pc8;
  const bf16* Brd = Bs + (wn + lm)*32 + pc8;

  for (int k0 = 0; k0 < 128; k0 += 32){
    gload16(Ag + k0,             AsW);
    gload16(Ag + 16*128 + k0,    AsW + 16*32);
    gload16(Bg + k0,             BsW);
    gload16(Bg + 16*128 + k0,    BsW + 16*32);
    __syncthreads();
    short8 af[4], bfv[4];
    #pragma unroll
    for (int i=0;i<4;i++) af[i]  = *(const short8*)(Ard + i*16*32);
    #pragma unroll
    for (int j=0;j<4;j++) bfv[j] = *(const short8*)(Brd + j*16*32);
    #pragma unroll
    for (int i=0;i<4;i++)
      #pragma unroll
      for (int j=0;j<4;j++)
        acc[i][j] = __builtin_amdgcn_mfma_f32_16x16x32_bf16(af[i], bfv[j], acc[i][j], 0, 0, 0);
    __syncthreads();
  }
  // attn dot partials + reductions
  float alv[4], arv[4];
  #pragma unroll
  for (int j=0;j<4;j++){
    int c = h*128 + wn + j*16 + lm;
    alv[j] = al[c]; arv[j] = ar[c];
  }
  int wnh = wave & 1;
  #pragma unroll
  for (int i=0;i<4;i++){
    #pragma unroll
    for (int rg=0; rg<4; rg++){
      float se = 0.f, sr = 0.f;
      #pragma unroll
      for (int j=0;j<4;j++){
        float v = acc[i][j][rg];
        se = fmaf(v, alv[j], se);
        sr = fmaf(v, arv[j], sr);
      }
      #pragma unroll
      for (int msk=1; msk<16; msk<<=1){
        se += __shfl_xor(se, msk);
        sr += __shfl_xor(sr, msk);
      }
      if (lm == 0){
        int rl = wm + i*16 + lq*4 + rg;
        redE[0][wnh][rl] = se;
        redE[1][wnh][rl] = sr;
      }
    }
  }
  // F store (bf16)
  #pragma unroll
  for (int i=0;i<4;i++){
    #pragma unroll
    for (int j=0;j<4;j++){
      int c = h*128 + wn + j*16 + lm;
      #pragma unroll
      for (int rg=0; rg<4; rg++){
        int r = r0 + wm + i*16 + lq*4 + rg;
        if (r < M) Fb[(size_t)r*512 + c] = __float2bfloat16(acc[i][j][rg]);
      }
    }
  }
  __syncthreads();
  if (tid < 128){
    int r = r0 + tid;
    if (r < M) el[(size_t)r*4 + h] = redE[0][0][tid] + redE[0][1][tid];
  } else {
    int t2 = tid - 128;
    int r = r0 + t2;
    if (r < M) er[(size_t)r*4 + h] = redE[1][0][t2] + redE[1][1][t2];
  }
}

// ====== memory GEMM v2: C[r,o] (+)= sum_m cf[r,m] * (feat[src[r]] . B[t][o, m*128..])
// per-m MFMA accumulator, coef folded at C-side. 64-row tiles, grid (M/64, nT).
// mode 0: Cb[r*128+o] = bf16(acc)   (rel: msg)
// mode 2: fout = lrelu(C[r,o] + acc) + trans[r,o]   (node + final fuse)
__global__ __launch_bounds__(256) void k_memgemm(
    const float* __restrict__ feat, const int* __restrict__ src,
    const float* __restrict__ coef, const bf16* __restrict__ B,
    float* __restrict__ C, bf16* __restrict__ Cb,
    const float* __restrict__ trans, float* __restrict__ fout,
    long srcStr, long coefStr, long Bstr, long CbStr,
    int Mvalid, int mode)
{
  __shared__ bf16 Af[64*144];        // 64 rows x 128 cols, stride 144 (16B-aligned rows)
  __shared__ float cfS[8*64];        // [m][row]
  __shared__ bf16 Bs[2][128*32];
  int t = blockIdx.y;
  const int*   srcT  = src ? src + (size_t)t*srcStr : nullptr;
  const float* coefT = coef + (size_t)t*coefStr;
  const bf16*  Bt    = B + (size_t)t*Bstr;
  int tid = threadIdx.x, wave = tid >> 6, lane = tid & 63;
  int r0 = blockIdx.x * 64;

  // ---- stage 64 feat rows (fp32 -> bf16) ----
  {
    int rL = tid >> 2, seg = tid & 3;
    int r = r0 + rL;
    bool valid = r < Mvalid;
    int s = valid ? (srcT ? srcT[r] : r) : 0;
    const float4* fp = (const float4*)(feat + (size_t)s*128 + seg*32);
    bf16* ap = Af + rL*144 + seg*32;
    #pragma unroll
    for (int q=0;q<8;q+=2){
      float4 v0 = fp[q], v1 = fp[q+1];
      __hip_bfloat162 p0 = __float22bfloat162_rn(make_float2(v0.x, v0.y));
      __hip_bfloat162 p1 = __float22bfloat162_rn(make_float2(v0.z, v0.w));
      __hip_bfloat162 p2 = __float22bfloat162_rn(make_float2(v1.x, v1.y));
      __hip_bfloat162 p3 = __float22bfloat162_rn(make_float2(v1.z, v1.w));
      *(__hip_bfloat162*)(ap + q*4)     = p0;
      *(__hip_bfloat162*)(ap + q*4 + 2) = p1;
      *(__hip_bfloat162*)(ap + q*4 + 4) = p2;
      *(__hip_bfloat162*)(ap + q*4 + 6) = p3;
    }
  }
  // ---- stage coef transposed: cfS[m][r] ----
  if (tid < 64){
    int r = r0 + tid;
    bool valid = r < Mvalid;
    #pragma unroll
    for (int m=0;m<8;m++)
      cfS[m*64 + tid] = valid ? coefT[(size_t)r*8 + m] : 0.f;
  }

  int rq = lane >> 2;
  int cg = stage_cg(lane);
  const bf16* Bg0 = Bt + (size_t)(wave*32 + rq)*1024 + cg;
  const bf16* Bg1 = Bt + (size_t)(wave*32 + 16 + rq)*1024 + cg;

  int wm = (wave >> 1) * 32, wn = (wave & 1) * 64;
  int lm = lane & 15, lq = lane >> 4;
  int pc8 = read_pc8(lm, lq);

  f32x4 accC[2][4];
  #pragma unroll
  for (int i=0;i<2;i++)
    #pragma unroll
    for (int j=0;j<4;j++) accC[i][j] = (f32x4){0.f,0.f,0.f,0.f};

  // prefetch first B k-tile
  {
    bf16* d = Bs[0] + wave*1024;
    gload16(Bg0, d);
    gload16(Bg1, d + 512);
  }
  __syncthreads();   // covers Af/cfS staging too

  int buf = 0;
  #pragma unroll
  for (int m = 0; m < 8; m++){
    f32x4 accM[2][4];
    #pragma unroll
    for (int ic = 0; ic < 4; ic++){
      int kk = m*4 + ic;
      if (kk + 1 < 32){
        int k1 = (kk + 1) * 32;
        bf16* d = Bs[buf^1] + wave*1024;
        gload16(Bg0 + k1, d);
        gload16(Bg1 + k1, d + 512);
      }
      short8 af[2], bfv[4];
      #pragma unroll
      for (int i=0;i<2;i++)
        af[i] = *(const short8*)(Af + (size_t)(wm + i*16 + lm)*144 + ic*32 + lq*8);
      #pragma unroll
      for (int j=0;j<4;j++)
        bfv[j] = *(const short8*)(Bs[buf] + (wn + lm + j*16)*32 + pc8);
      if (ic == 0){
        #pragma unroll
        for (int i=0;i<2;i++)
          #pragma unroll
          for (int j=0;j<4;j++)
            accM[i][j] = __builtin_amdgcn_mfma_f32_16x16x32_bf16(af[i], bfv[j],
                             (f32x4){0.f,0.f,0.f,0.f}, 0, 0, 0);
      } else {
        #pragma unroll
        for (int i=0;i<2;i++)
          #pragma unroll
          for (int j=0;j<4;j++)
            accM[i][j] = __builtin_amdgcn_mfma_f32_16x16x32_bf16(af[i], bfv[j], accM[i][j], 0, 0, 0);
      }
      __syncthreads();
      buf ^= 1;
    }
    // fold coef at C side
    #pragma unroll
    for (int i=0;i<2;i++){
      f32x4 cf4 = *(const f32x4*)(cfS + m*64 + wm + i*16 + lq*4);
      #pragma unroll
      for (int j=0;j<4;j++)
        #pragma unroll
        for (int rg=0; rg<4; rg++)
          accC[i][j][rg] = fmaf(cf4[rg], accM[i][j][rg], accC[i][j][rg]);
    }
  }
  // epilogue
  #pragma unroll
  for (int i=0;i<2;i++){
    #pragma unroll
    for (int j=0;j<4;j++){
      int c = wn + j*16 + lm;
      #pragma unroll
      for (int rg=0; rg<4; rg++){
        int r = r0 + wm + i*16 + lq*4 + rg;
        if (r < Mvalid){
          float v = accC[i][j][rg];
          if (mode == 0){
            Cb[(size_t)t*CbStr + (size_t)r*128 + c] = __float2bfloat16(v);
          } else {
            float x = C[(size_t)r*128 + c] + v;
            x = x>0.f ? x : 0.2f*x;
            fout[(size_t)r*128 + c] = x + trans[(size_t)r*128 + c];
          }
        }
      }
    }
  }
}

// ---------- fp32 -> bf16 with zero pad ----------
__global__ void k_f2b(const float* __restrict__ in, bf16* __restrict__ o, int nv, int nt){
  int i = blockIdx.x*256 + threadIdx.x;
  if (i < nt) o[i] = __float2bfloat16(i < nv ? in[i] : 0.f);
}

// ---------- repack Ww (M,Do,Di) -> B^T [Do x (M*Di)] bf16, per slice ----------
__global__ void k_repack(const float* __restrict__ in, bf16* __restrict__ o){
  int s = blockIdx.y;
  int g = blockIdx.x*256 + threadIdx.x;          // g = m*16384 + od*128 + i
  int m = g >> 14, od = (g >> 7) & 127, i = g & 127;
  o[(size_t)s*131072 + (size_t)od*1024 + m*128 + i] = __float2bfloat16(in[(size_t)s*131072 + g]);
}

// ---------- CSR build ----------
__global__ void k_hist(const int* __restrict__ dIdx, int* __restrict__ cnt, int E){
  int e = blockIdx.x*256+threadIdx.x;
  if (e<E) atomicAdd(&cnt[dIdx[e]], 1);
}

__global__ __launch_bounds__(1024) void k_scan(const int* __restrict__ in,
                                               int* __restrict__ out, int n){
  __shared__ int wsum[16];
  __shared__ int carry;
  int tidx = threadIdx.x, lane = tidx & 63, w = tidx >> 6;
  if (tidx == 0) carry = 0;
  __syncthreads();
  for (int base = 0; base < n; base += 1024){
    int i = base + tidx;
    int v = (i < n) ? in[i] : 0;
    int x = v;
    #pragma unroll
    for (int off = 1; off < 64; off <<= 1){
      int t = __shfl_up(x, off);
      if (lane >= off) x += t;
    }
    if (lane == 63) wsum[w] = x;
    __syncthreads();
    if (w == 0 && lane < 16){
      int t = wsum[lane];
      #pragma unroll
      for (int off=1; off<16; off<<=1){
        int u = __shfl_up(t, off, 16);
        if (lane >= off) t += u;
      }
      wsum[lane] = t;
    }
    __syncthreads();
    int woff = (w == 0) ? 0 : wsum[w-1];
    int excl = carry + woff + x - v;
    if (i < n) out[i] = excl;
    __syncthreads();
    if (tidx == 1023) carry = carry + wsum[15];
    __syncthreads();
  }
  if (tidx == 0) out[n] = carry;
}

__global__ void k_csr_scatter(const int* __restrict__ sIdx, const int* __restrict__ dIdx,
                              int sOff, const int* __restrict__ rowptr,
                              int* __restrict__ cursor, int* __restrict__ col, int E){
  int e = blockIdx.x*256+threadIdx.x; if (e>=E) return;
  int d = dIdx[e];
  int pos = rowptr[d] + atomicAdd(&cursor[d], 1);
  col[pos] = sIdx[e] + sOff;
}

__global__ void k_csr_scatter_eid(const int* __restrict__ dIdx, const int* __restrict__ rowptr,
                                  int* __restrict__ cursor, int* __restrict__ col, int E){
  int e = blockIdx.x*256+threadIdx.x; if (e>=E) return;
  int d = dIdx[e];
  int pos = rowptr[d] + atomicAdd(&cursor[d], 1);
  col[pos] = e;
}

// ------- fused GAT aggregation: online softmax + bf16 gather + rstb epilogue -------
// rstb[dl, c] = bf16(elu(softmax-weighted-sum + gb[c]))
__global__ __launch_bounds__(64) void k_gat_gather(
    const int* __restrict__ rowptr, const int* __restrict__ col,
    const float* __restrict__ el, const float* __restrict__ er,
    const bf16* __restrict__ Fb, const float* __restrict__ gb,
    bf16* __restrict__ rstb, int dOff)
{
  int dl = blockIdx.x;
  int lane = threadIdx.x;
  int h = lane >> 4;
  int off = (lane & 15) << 3;
  float erh = er[(size_t)(dl + dOff)*4 + h];
  float m = -INFINITY, den = 0.f;
  float acc[8];
  #pragma unroll
  for (int i=0;i<8;i++) acc[i]=0.f;
  int jb = rowptr[dl], je = rowptr[dl+1];
  for (int j=jb; j<je; j++){
    int s = col[j];
    float e = el[(size_t)s*4+h] + erh;
    e = e > 0.f ? e : 0.2f*e;
    float mn = fmaxf(m, e);
    float sc = __expf(m - mn);
    float wj = __expf(e - mn);
    den = den*sc + wj;
    m = mn;
    uint4 u = *(const uint4*)(Fb + (size_t)s*512 + h*128 + off);
    acc[0]=acc[0]*sc + wj*bu2f_lo(u.x); acc[1]=acc[1]*sc + wj*bu2f_hi(u.x);
    acc[2]=acc[2]*sc + wj*bu2f_lo(u.y); acc[3]=acc[3]*sc + wj*bu2f_hi(u.y);
    acc[4]=acc[4]*sc + wj*bu2f_lo(u.z); acc[5]=acc[5]*sc + wj*bu2f_hi(u.z);
    acc[6]=acc[6]*sc + wj*bu2f_lo(u.w); acc[7]=acc[7]*sc + wj*bu2f_hi(u.w);
  }
  float inv = den > 0.f ? 1.f/den : 0.f;
  int cb = h*128 + off;
  float x[8];
  #pragma unroll
  for (int q=0;q<8;q++){
    float v = acc[q]*inv + gb[cb+q];
    x[q] = v>0.f ? v : expm1f(v);
  }
  union { uint4 u; __hip_bfloat162 p[4]; } O;
  #pragma unroll
  for (int q=0;q<4;q++) O.p[q] = __float22bfloat162_rn(make_float2(x[2*q], x[2*q+1]));
  *(uint4*)(rstb + (size_t)dl*512 + cb) = O.u;
}

// ---------- coef / ncoef: lrelu(x @ Wc^T + bc), M=8 outputs ----------
__global__ void k_coef(const float* __restrict__ feat, const int* __restrict__ idx,
                       const float* __restrict__ Wc, const float* __restrict__ bc,
                       float* __restrict__ outc, int cnt){
  int t = blockIdx.y;
  __shared__ float wS[MMEM*DD];
  __shared__ float bS[MMEM];
  for (int i=threadIdx.x;i<MMEM*DD;i+=128) wS[i] = Wc[(size_t)t*MMEM*DD + i];
  if (threadIdx.x < MMEM) bS[threadIdx.x] = bc[t*MMEM + threadIdx.x];
  __syncthreads();
  int e = blockIdx.x*128 + threadIdx.x; if (e >= cnt) return;
  int node = idx ? idx[(size_t)t*cnt + e] : e;
  float acc[MMEM];
  #pragma unroll
  for (int m=0;m<MMEM;m++) acc[m]=bS[m];
  const float* fr = feat + (size_t)node*DD;
  for (int d2=0; d2<DD; d2++){
    float v = fr[d2];
    #pragma unroll
    for (int m=0;m<MMEM;m++) acc[m] = fmaf(v, wS[m*DD+d2], acc[m]);
  }
  float* op = outc + ((size_t)t*cnt + e)*MMEM;
  #pragma unroll
  for (int m=0;m<MMEM;m++){ float v=acc[m]; op[m] = v>0.f ? v : 0.2f*v; }
}

// ---------- memory segment-sum gather (bf16 msg) ----------
__global__ void k_mem_gather(const int* __restrict__ rpT, const int* __restrict__ colT,
                             const bf16* __restrict__ msg, float* __restrict__ sAgg){
  int n = blockIdx.x*4 + (threadIdx.x >> 6);
  if (n >= NTOT) return;
  int lane = threadIdx.x & 63;
  int jb = rpT[n], je = rpT[n+1];
  float a0=0.f, a1=0.f;
  for (int j=jb;j<je;j++){
    unsigned u = ((const unsigned*)(msg + (size_t)colT[j]*128))[lane];
    a0 += bu2f_lo(u); a1 += bu2f_hi(u);
  }
  *(float2*)(sAgg + (size_t)n*128 + lane*2) = make_float2(a0, a1);
}

// ---------- memory LN ----------
__global__ void k_memln(const float* __restrict__ s, const int* __restrict__ rpT,
                        const float* __restrict__ lw, const float* __restrict__ lb,
                        const float* __restrict__ hb, float* __restrict__ outp){
  int n = blockIdx.x, lane = threadIdx.x;
  float c = fmaxf((float)(rpT[n+1]-rpT[n]), 1.f);
  float x1 = s[(size_t)n*128+lane]/c, x2 = s[(size_t)n*128+64+lane]/c;
  float t = x1+x2;
  #pragma unroll
  for (int off=32;off;off>>=1) t += __shfl_xor(t,off);
  float mu = t * (1.f/128.f);
  float d1=x1-mu, d2=x2-mu;
  float v = d1*d1+d2*d2;
  #pragma unroll
  for (int off=32;off;off>>=1) v += __shfl_xor(v,off);
  float r = rsqrtf(v*(1.f/128.f) + 1e-5f);
  outp[(size_t)n*128+lane]    = d1*r*lw[lane]    + lb[lane]    + hb[lane];
  outp[(size_t)n*128+64+lane] = d2*r*lw[64+lane] + lb[64+lane] + hb[64+lane];
}

// ---------- final LN over 384-wide concat ----------
__global__ void k_final_ln(const float* __restrict__ emb, const float* __restrict__ f1,
                           const float* __restrict__ f2, const float* __restrict__ w,
                           const float* __restrict__ b, float* __restrict__ out){
  int n = blockIdx.x, t = threadIdx.x;
  __shared__ float red[4];
  float x0 = emb[(size_t)n*128+t];
  float x1 = f1[(size_t)n*128+t];
  float x2 = f2[(size_t)n*128+t];
  float s = x0+x1+x2;
  #pragma unroll
  for (int off=32;off;off>>=1) s += __shfl_xor(s,off);
  if ((t&63)==0) red[t>>6] = s;
  __syncthreads();
  float mu = (red[0]+red[1]) * (1.f/384.f);
  float d0=x0-mu, d1=x1-mu, d2=x2-mu;
  float v = d0*d0+d1*d1+d2*d2;
  #pragma unroll
  for (int off=32;off;off>>=1) v += __shfl_xor(v,off);
  if ((t&63)==0) red[2+(t>>6)] = v;
  __syncthreads();
  float var = (red[2]+red[3]) * (1.f/384.f);
  float r = rsqrtf(var + 1e-5f);
  size_t o = (size_t)n*384;
  out[o+t]     = d0*r*w[t]     + b[t];
  out[o+128+t] = d1*r*w[128+t] + b[128+t];
  out[o+256+t] = d2*r*w[256+t] + b[256+t];
}

extern "C" void kernel_launch(void* const* d_in, const int* in_sizes, int n_in,
                              void* d_out, int out_size, void* d_ws, size_t ws_size,
                              hipStream_t stream)
{
  const float* emb   = (const float*)d_in[0];
  const float* fcW   = (const float*)d_in[1];
  const float* attl  = (const float*)d_in[2];
  const float* attr  = (const float*)d_in[3];
  const float* gbias = (const float*)d_in[4];
  const float* projW = (const float*)d_in[5];
  const float* projB = (const float*)d_in[6];
  const float* relWc = (const float*)d_in[7];
  const float* relbc = (const float*)d_in[8];
  const float* relWw = (const float*)d_in[9];
  const float* nodWc = (const float*)d_in[10];
  const float* nodbc = (const float*)d_in[11];
  const float* nodWw = (const float*)d_in[12];
  const float* hbias = (const float*)d_in[13];
  const float* mlnw  = (const float*)d_in[14];
  const float* mlnb  = (const float*)d_in[15];
  const float* flnw  = (const float*)d_in[16];
  const float* flnb  = (const float*)d_in[17];
  const int*  srcU  = (const int*)d_in[18];
  const int*  dstI  = (const int*)d_in[19];
  const int*  eSrc  = (const int*)d_in[20];
  const int*  eDst  = (const int*)d_in[21];
  float* out = (float*)d_out;

  char* wp = (char*)d_ws;
  auto alloc = [&](size_t bytes)->void* {
    void* p = (void*)wp; wp += (bytes + 511) & ~(size_t)511; return p;
  };
  float* feat1 = (float*)alloc((size_t)NTOT*DD*4);
  float* feat2 = (float*)alloc((size_t)NTOT*DD*4);
  float* Fbuf  = (float*)alloc((size_t)NTOT*512*4);         // overlay region (82 MB)
  float* rst   = (float*)alloc((size_t)NTOT*DD*2*4);        // sAgg + memO (41 MB)
  bf16*  rstb0 = (bf16*)alloc((size_t)2*MP_H*512*2);        // rstb dir0+dir1
  float* trans = (float*)alloc((size_t)NTOT*DD*4);
  float* elF   = (float*)alloc((size_t)NTOT*4*4);
  float* erF   = (float*)alloc((size_t)NTOT*4*4);
  int* rpA  = (int*)alloc((size_t)(NUSER+1)*4);
  int* colA = (int*)alloc((size_t)EUI*4);
  int* rpB  = (int*)alloc((size_t)(NITEM+1)*4);
  int* colB = (int*)alloc((size_t)EUI*4);
  int* icnt = (int*)alloc((size_t)20000*4);
  int* icur = (int*)alloc((size_t)20000*4);
  int* rpT  = (int*)alloc((size_t)(NTOT+1)*4);
  int* colT = (int*)alloc((size_t)TT*ET*4);
  int* cntT = (int*)alloc((size_t)NTOT*4);
  int* icurT= (int*)alloc((size_t)NTOT*4);
  bf16* featb  = (bf16*)alloc((size_t)MP_N*DD*2);
  bf16* fcWb   = (bf16*)alloc((size_t)4*512*DD*2);
  bf16* projWb = (bf16*)alloc((size_t)4*DD*512*2);
  bf16* relWwb = (bf16*)alloc((size_t)10*DD*1024*2);
  bf16* nodWwb = (bf16*)alloc((size_t)2*DD*1024*2);
  // overlays in Fbuf:
  bf16*  Fb     = (bf16*)Fbuf;                                    // NTOT*512 bf16 (41 MB)
  bf16*  msgBb  = (bf16*)((char*)Fbuf + (size_t)NTOT*512*2);      // 5*ET*128 bf16
  float* coefB  = (float*)((char*)msgBb + (size_t)TT*ET*128*2);   // 5*ET*8 fp32
  float* ncoefB = coefB + (size_t)TT*ET*8;                        // NTOT*8 fp32
  bf16*  rstb1  = rstb0 + (size_t)MP_H*512;
  float* sAgg   = rst;
  float* memO   = rst + (size_t)NTOT*DD;

  // ---- one-time: weight conversion/repack ----
  k_f2b<<<dim3((4*512*DD+255)/256),256,0,stream>>>(fcW, fcWb, 4*512*DD, 4*512*DD);
  k_f2b<<<dim3((4*DD*512+255)/256),256,0,stream>>>(projW, projWb, 4*DD*512, 4*DD*512);
  k_repack<<<dim3(512,10),256,0,stream>>>(relWw, relWwb);
  k_repack<<<dim3(512,2),256,0,stream>>>(nodWw, nodWwb);
  // zero rstb padding rows (re-poisoned every launch)
  hipMemsetAsync(rstb0 + (size_t)20000*512, 0, (size_t)(MP_H-20000)*512*2, stream);
  hipMemsetAsync(rstb1 + (size_t)20000*512, 0, (size_t)(MP_H-20000)*512*2, stream);

  // ---- one-time: CSR builds ----
  hipMemsetAsync(icnt, 0, 20000*4, stream);
  hipMemsetAsync(icur, 0, 20000*4, stream);
  k_hist<<<dim3((EUI+255)/256),256,0,stream>>>(srcU, icnt, EUI);
  k_scan<<<dim3(1),1024,0,stream>>>(icnt, rpA, NUSER);
  k_csr_scatter<<<dim3((EUI+255)/256),256,0,stream>>>(dstI, srcU, NUSER, rpA, icur, colA, EUI);
  hipMemsetAsync(icnt, 0, 20000*4, stream);
  hipMemsetAsync(icur, 0, 20000*4, stream);
  k_hist<<<dim3((EUI+255)/256),256,0,stream>>>(dstI, icnt, EUI);
  k_scan<<<dim3(1),1024,0,stream>>>(icnt, rpB, NITEM);
  k_csr_scatter<<<dim3((EUI+255)/256),256,0,stream>>>(srcU, dstI, 0, rpB, icur, colB, EUI);
  hipMemsetAsync(cntT, 0, NTOT*4, stream);
  hipMemsetAsync(icurT, 0, NTOT*4, stream);
  k_hist<<<dim3((TT*ET+255)/256),256,0,stream>>>(eDst, cntT, TT*ET);
  k_scan<<<dim3(1),1024,0,stream>>>(cntT, rpT, NTOT);
  k_csr_scatter_eid<<<dim3((TT*ET+255)/256),256,0,stream>>>(eDst, rpT, icurT, colT, TT*ET);

  const float* feats[3] = {emb, feat1, feat2};
  for (int l=0; l<2; l++){
    const float* fin  = feats[l];
    float* fout = (float*)feats[l+1];

    k_f2b<<<dim3((MP_N*DD+255)/256),256,0,stream>>>(fin, featb, NTOT*DD, MP_N*DD);

    for (int d=0; d<2; d++){
      // F = feat @ W^T fused with attn dots; bf16 F out
      k_fc_gemm<<<dim3(MP_N/128, 4),256,0,stream>>>(
          featb, fcWb + (size_t)(l*2+d)*512*DD, Fb,
          attl+(size_t)(l*2+d)*512, attr+(size_t)(l*2+d)*512, elF, erF, NTOT);
      int dOff = (d==0) ? 0 : NUSER;
      const int* rp  = (d==0) ? rpA : rpB;
      const int* col = (d==0) ? colA : colB;
      // gather fused with elu(rst+gbias) -> bf16
      k_gat_gather<<<dim3(20000),64,0,stream>>>(rp, col, elF, erF, Fb,
          gbias+(size_t)(l*2+d)*512, (d==0) ? rstb0 : rstb1, dOff);
    }
    // proj both directions in one dispatch: M=20000, N=128, K=512
    k_mfma_gemm<<<dim3(MP_H/128, 1, 2),256,0,stream>>>(
        rstb0, projWb + (size_t)(l*2)*DD*512, projB + (size_t)(l*2)*DD, trans,
        (long)MP_H*512, (long)DD*512, (long)DD, (long)20000*DD,
        DD, 20000, 512, 1, 0);

    // ---- memory layer ----
    k_coef<<<dim3((ET+127)/128, TT),128,0,stream>>>(fin, eDst,
        relWc+(size_t)l*TT*MMEM*DD, relbc+(size_t)l*TT*MMEM, coefB, ET);
    k_memgemm<<<dim3(ET/64, TT),256,0,stream>>>(
        fin, eSrc, coefB, relWwb + (size_t)l*TT*DD*1024,
        nullptr, msgBb, nullptr, nullptr,
        (long)ET, (long)ET*8, (long)DD*1024, (long)ET*128, ET, 0);
    k_mem_gather<<<dim3(NTOT/4),256,0,stream>>>(rpT, colT, msgBb, sAgg);
    k_memln<<<dim3(NTOT),64,0,stream>>>(sAgg, rpT, mlnw+(size_t)l*DD, mlnb+(size_t)l*DD,
                                        hbias+(size_t)l*DD, memO);
    k_coef<<<dim3((NTOT+127)/128, 1),128,0,stream>>>(fin, nullptr,
        nodWc+(size_t)l*MMEM*DD, nodbc+(size_t)l*MMEM, ncoefB, NTOT);
    // node memgemm fused with lrelu(memO+acc)+trans -> fout
    k_memgemm<<<dim3(MP_N/64, 1),256,0,stream>>>(
        fin, nullptr, ncoefB, nodWwb + (size_t)l*DD*1024,
        memO, nullptr, trans, fout,
        0, 0, 0, 0, NTOT, 2);
  }

  k_final_ln<<<dim3(NTOT),128,0,stream>>>(emb, feat1, feat2, flnw, flnb, out);
}